// Round 1
// baseline (6772.419 us; speedup 1.0000x reference)
//
#include <hip/hip_runtime.h>

#define METAc 3
#define Nn 50000
#define Ee 640000
#define Fc 128
#define Hc 128
#define Dc 64

// ---------------- degree ----------------
__global__ __launch_bounds__(256) void k_degree(const int* __restrict__ ei, float* __restrict__ deg) {
    int idx = blockIdx.x * 256 + threadIdx.x;
    if (idx >= METAc * Ee) return;
    int m = idx / Ee, e = idx - m * Ee;
    int dst = ei[(size_t)m * 2 * Ee + Ee + e];
    atomicAdd(deg + m * Nn + dst, 1.0f);
}

__global__ __launch_bounds__(256) void k_invdeg(float* deg) {
    int idx = blockIdx.x * 256 + threadIdx.x;
    if (idx >= METAc * Nn) return;
    deg[idx] = 1.0f / fmaxf(deg[idx], 1.0f);
}

// ---------------- scatter-add: agg[dst] += feat[src], C=128 ----------------
__global__ __launch_bounds__(256) void k_scatter(const float* __restrict__ src_feat,
                                                 const int* __restrict__ ei,
                                                 float* __restrict__ agg) {
    int idx = blockIdx.x * 256 + threadIdx.x;   // over META*E*32 (float4 granules)
    if (idx >= METAc * Ee * 32) return;
    int c4 = idx & 31;
    int eg = idx >> 5;
    int m = eg / Ee, e = eg - m * Ee;
    const int* eim = ei + (size_t)m * 2 * Ee;
    int s = eim[e], d = eim[Ee + e];
    const float4 v = *(const float4*)(src_feat + ((size_t)m * Nn + s) * 128 + c4 * 4);
    float* a = agg + ((size_t)m * Nn + d) * 128 + c4 * 4;
    atomicAdd(a + 0, v.x);
    atomicAdd(a + 1, v.y);
    atomicAdd(a + 2, v.z);
    atomicAdd(a + 3, v.w);
}

// ---------------- GEMM1: h = ELU([mean,x] @ [W1l;W1r] + b1), cols=128 ----------------
__global__ __launch_bounds__(256) void k_gemm1(
    const float* __restrict__ agg, const float* __restrict__ x,
    const float* __restrict__ invdeg,
    const float* __restrict__ W1l, const float* __restrict__ W1r,
    const float* __restrict__ b1, float* __restrict__ h)
{
    const int m = blockIdx.y;
    const int row0 = blockIdx.x * 64;
    const int tid = threadIdx.x;
    const int tx = tid & 15, ty = tid >> 4;

    __shared__ float As[64][68];     // 64 rows x 64 k-chunk, padded for 16B-aligned rows
    __shared__ float Ws[64][128];    // k-major weight tile
    __shared__ float inv_s[64];

    if (tid < 64) {
        int r = row0 + tid;
        inv_s[tid] = (r < Nn) ? invdeg[m * Nn + r] : 0.0f;
    }

    float acc[4][8];
    #pragma unroll
    for (int i = 0; i < 4; i++)
        #pragma unroll
        for (int j = 0; j < 8; j++) acc[i][j] = 0.0f;

    const float* Asrc0 = agg + (size_t)m * Nn * 128;
    const float* Asrc1 = x   + (size_t)m * Nn * 128;
    const float* Wsrc0 = W1l + (size_t)m * 128 * 128;
    const float* Wsrc1 = W1r + (size_t)m * 128 * 128;

    for (int kk = 0; kk < 256; kk += 64) {
        __syncthreads();
        const bool first = kk < 128;
        const int kbase = first ? kk : kk - 128;
        // A tile: 64 rows x 64 k (1024 float4s / 256 threads = 4 each)
        #pragma unroll
        for (int i = 0; i < 4; i++) {
            int f4 = tid + i * 256;
            int row = f4 >> 4;
            int col4 = f4 & 15;
            int grow = row0 + row;
            int gr = grow < Nn ? grow : Nn - 1;
            const float* p = (first ? Asrc0 : Asrc1) + (size_t)gr * 128 + kbase + col4 * 4;
            float4 v = *(const float4*)p;
            if (first) { float s = inv_s[row]; v.x *= s; v.y *= s; v.z *= s; v.w *= s; }
            *(float4*)&As[row][col4 * 4] = v;
        }
        // W tile: 64 k x 128 cols (2048 float4s / 256 threads = 8 each)
        #pragma unroll
        for (int i = 0; i < 8; i++) {
            int f4 = tid + i * 256;
            int row = f4 >> 5;
            int col4 = f4 & 31;
            const float* p = (first ? Wsrc0 : Wsrc1) + (size_t)(kbase + row) * 128 + col4 * 4;
            *(float4*)&Ws[row][col4 * 4] = *(const float4*)p;
        }
        __syncthreads();
        #pragma unroll
        for (int k = 0; k < 64; k++) {
            float a[4];
            #pragma unroll
            for (int r = 0; r < 4; r++) a[r] = As[ty * 4 + r][k];
            float4 w0 = *(const float4*)&Ws[k][tx * 8];
            float4 w1 = *(const float4*)&Ws[k][tx * 8 + 4];
            float w[8] = {w0.x, w0.y, w0.z, w0.w, w1.x, w1.y, w1.z, w1.w};
            #pragma unroll
            for (int r = 0; r < 4; r++)
                #pragma unroll
                for (int c = 0; c < 8; c++)
                    acc[r][c] += a[r] * w[c];
        }
    }

    const int j0 = tx * 8;
    float bias[8];
    #pragma unroll
    for (int c = 0; c < 8; c++) bias[c] = b1[m * 128 + j0 + c];
    #pragma unroll
    for (int r = 0; r < 4; r++) {
        int grow = row0 + ty * 4 + r;
        if (grow >= Nn) continue;
        float o[8];
        #pragma unroll
        for (int c = 0; c < 8; c++) {
            float v = acc[r][c] + bias[c];
            o[c] = v > 0.0f ? v : expm1f(v);   // ELU (alpha=1)
        }
        float4* p = (float4*)(h + ((size_t)m * Nn + grow) * 128 + j0);
        p[0] = make_float4(o[0], o[1], o[2], o[3]);
        p[1] = make_float4(o[4], o[5], o[6], o[7]);
    }
}

// ---------------- GEMM2: out = log_softmax([mean,h] @ [W2l;W2r] + b2), cols=64 ----------------
__global__ __launch_bounds__(256) void k_gemm2(
    const float* __restrict__ agg, const float* __restrict__ h,
    const float* __restrict__ invdeg,
    const float* __restrict__ W2l, const float* __restrict__ W2r,
    const float* __restrict__ b2, float* __restrict__ out)
{
    const int m = blockIdx.y;
    const int row0 = blockIdx.x * 64;
    const int tid = threadIdx.x;
    const int tx = tid & 15, ty = tid >> 4;

    __shared__ float As[64][68];
    __shared__ float Ws[64][64];
    __shared__ float inv_s[64];

    if (tid < 64) {
        int r = row0 + tid;
        inv_s[tid] = (r < Nn) ? invdeg[m * Nn + r] : 0.0f;
    }

    float acc[4][4];
    #pragma unroll
    for (int i = 0; i < 4; i++)
        #pragma unroll
        for (int j = 0; j < 4; j++) acc[i][j] = 0.0f;

    const float* Asrc0 = agg + (size_t)m * Nn * 128;
    const float* Asrc1 = h   + (size_t)m * Nn * 128;
    const float* Wsrc0 = W2l + (size_t)m * 128 * 64;
    const float* Wsrc1 = W2r + (size_t)m * 128 * 64;

    for (int kk = 0; kk < 256; kk += 64) {
        __syncthreads();
        const bool first = kk < 128;
        const int kbase = first ? kk : kk - 128;
        #pragma unroll
        for (int i = 0; i < 4; i++) {
            int f4 = tid + i * 256;
            int row = f4 >> 4;
            int col4 = f4 & 15;
            int grow = row0 + row;
            int gr = grow < Nn ? grow : Nn - 1;
            const float* p = (first ? Asrc0 : Asrc1) + (size_t)gr * 128 + kbase + col4 * 4;
            float4 v = *(const float4*)p;
            if (first) { float s = inv_s[row]; v.x *= s; v.y *= s; v.z *= s; v.w *= s; }
            *(float4*)&As[row][col4 * 4] = v;
        }
        // W tile: 64 k x 64 cols (1024 float4s / 256 threads = 4 each)
        #pragma unroll
        for (int i = 0; i < 4; i++) {
            int f4 = tid + i * 256;
            int row = f4 >> 4;
            int col4 = f4 & 15;
            const float* p = (first ? Wsrc0 : Wsrc1) + (size_t)(kbase + row) * 64 + col4 * 4;
            *(float4*)&Ws[row][col4 * 4] = *(const float4*)p;
        }
        __syncthreads();
        #pragma unroll
        for (int k = 0; k < 64; k++) {
            float a[4];
            #pragma unroll
            for (int r = 0; r < 4; r++) a[r] = As[ty * 4 + r][k];
            float4 w = *(const float4*)&Ws[k][tx * 4];
            float wv[4] = {w.x, w.y, w.z, w.w};
            #pragma unroll
            for (int r = 0; r < 4; r++)
                #pragma unroll
                for (int c = 0; c < 4; c++)
                    acc[r][c] += a[r] * wv[c];
        }
    }

    const int j0 = tx * 4;
    float bias[4];
    #pragma unroll
    for (int c = 0; c < 4; c++) bias[c] = b2[m * 64 + j0 + c];

    #pragma unroll
    for (int r = 0; r < 4; r++) {
        int grow = row0 + ty * 4 + r;
        float z[4];
        #pragma unroll
        for (int c = 0; c < 4; c++) z[c] = acc[r][c] + bias[c];
        // row max across 16 lanes (each holding 4 of 64 cols)
        float mx = fmaxf(fmaxf(z[0], z[1]), fmaxf(z[2], z[3]));
        #pragma unroll
        for (int mask = 1; mask <= 8; mask <<= 1)
            mx = fmaxf(mx, __shfl_xor(mx, mask));
        float s = 0.0f;
        #pragma unroll
        for (int c = 0; c < 4; c++) s += expf(z[c] - mx);
        #pragma unroll
        for (int mask = 1; mask <= 8; mask <<= 1)
            s += __shfl_xor(s, mask);
        float lse = mx + logf(s);
        if (grow < Nn) {
            float4 o = make_float4(z[0] - lse, z[1] - lse, z[2] - lse, z[3] - lse);
            *(float4*)(out + ((size_t)m * Nn + grow) * 64 + j0) = o;
        }
    }
}

extern "C" void kernel_launch(void* const* d_in, const int* in_sizes, int n_in,
                              void* d_out, int out_size, void* d_ws, size_t ws_size,
                              hipStream_t stream) {
    const float* meta_x = (const float*)d_in[0];
    const int*   ei     = (const int*)d_in[1];
    const float* W1l    = (const float*)d_in[2];
    const float* W1r    = (const float*)d_in[3];
    const float* b1     = (const float*)d_in[4];
    const float* W2l    = (const float*)d_in[5];
    const float* W2r    = (const float*)d_in[6];
    const float* b2     = (const float*)d_in[7];
    float* out = (float*)d_out;

    float* deg = (float*)d_ws;                           // META*N
    float* agg = deg + (size_t)METAc * Nn;               // META*N*128
    float* h   = agg + (size_t)METAc * Nn * 128;         // META*N*128

    hipMemsetAsync(deg, 0, (size_t)METAc * Nn * sizeof(float), stream);
    hipMemsetAsync(agg, 0, (size_t)METAc * Nn * 128 * sizeof(float), stream);

    k_degree<<<(METAc * Ee + 255) / 256, 256, 0, stream>>>(ei, deg);
    k_invdeg<<<(METAc * Nn + 255) / 256, 256, 0, stream>>>(deg);

    k_scatter<<<(METAc * Ee * 32 + 255) / 256, 256, 0, stream>>>(meta_x, ei, agg);
    k_gemm1<<<dim3((Nn + 63) / 64, METAc), 256, 0, stream>>>(agg, meta_x, deg, W1l, W1r, b1, h);

    hipMemsetAsync(agg, 0, (size_t)METAc * Nn * 128 * sizeof(float), stream);
    k_scatter<<<(METAc * Ee * 32 + 255) / 256, 256, 0, stream>>>(h, ei, agg);
    k_gemm2<<<dim3((Nn + 63) / 64, METAc), 256, 0, stream>>>(agg, h, deg, W2l, W2r, b2, out);
}

// Round 2
// 881.933 us; speedup vs baseline: 7.6791x; 7.6791x over previous
//
#include <hip/hip_runtime.h>

#define METAc 3
#define Nn 50000
#define Ee 640000
#define CHUNK 1024
#define NCH 49   // ceil(Nn/CHUNK)

// ================= CSR build =================
__global__ __launch_bounds__(256) void k_count(const int* __restrict__ ei, int* __restrict__ cnt) {
    int idx = blockIdx.x * 256 + threadIdx.x;
    if (idx >= METAc * Ee) return;
    int m = idx / Ee, e = idx - m * Ee;
    int dst = ei[(size_t)m * 2 * Ee + Ee + e];
    atomicAdd(cnt + m * Nn + dst, 1);
}

// phase A: per-chunk sums
__global__ __launch_bounds__(1024) void k_chunksum(const int* __restrict__ cnt, int* __restrict__ csum) {
    int m = blockIdx.x / NCH, ch = blockIdx.x - m * NCH;
    int tid = threadIdx.x;
    int i = ch * CHUNK + tid;
    int v = (i < Nn) ? cnt[m * Nn + i] : 0;
    // wave reduce
    #pragma unroll
    for (int o = 1; o < 64; o <<= 1) v += __shfl_xor(v, o);
    __shared__ int ws_[16];
    int lane = tid & 63, w = tid >> 6;
    if (lane == 0) ws_[w] = v;
    __syncthreads();
    if (tid == 0) {
        int s = 0;
        #pragma unroll
        for (int k = 0; k < 16; k++) s += ws_[k];
        csum[m * 64 + ch] = s;
    }
}

// phase B: exclusive scan of chunk sums (one wave per graph)
__global__ __launch_bounds__(256) void k_chunkscan(int* __restrict__ csum) {
    int tid = threadIdx.x;
    int w = tid >> 6, lane = tid & 63;
    if (w >= METAc) return;
    int v = (lane < NCH) ? csum[w * 64 + lane] : 0;
    int orig = v;
    #pragma unroll
    for (int o = 1; o < 64; o <<= 1) { int t = __shfl_up(v, o); if (lane >= o) v += t; }
    if (lane < NCH) csum[w * 64 + lane] = v - orig;  // exclusive
}

// phase C: per-chunk exclusive scan + base -> off, cursor, inv
__global__ __launch_bounds__(1024) void k_scan(const int* __restrict__ cnt, const int* __restrict__ csum,
                                               int* __restrict__ off, int* __restrict__ cur,
                                               float* __restrict__ inv) {
    int m = blockIdx.x / NCH, ch = blockIdx.x - m * NCH;
    int tid = threadIdx.x;
    int i = ch * CHUNK + tid;
    int c = (i < Nn) ? cnt[m * Nn + i] : 0;
    int lane = tid & 63, w = tid >> 6;
    int v = c;
    #pragma unroll
    for (int o = 1; o < 64; o <<= 1) { int t = __shfl_up(v, o); if (lane >= o) v += t; }
    __shared__ int ws_[16];
    if (lane == 63) ws_[w] = v;
    __syncthreads();
    if (tid < 16) {
        int s = ws_[tid];
        #pragma unroll
        for (int o = 1; o < 16; o <<= 1) { int t = __shfl_up(s, o); if (lane >= o) s += t; }
        ws_[tid] = s;  // inclusive over waves
    }
    __syncthreads();
    int base = (w > 0) ? ws_[w - 1] : 0;
    if (i < Nn) {
        int g = csum[m * 64 + ch] + base + v - c;  // exclusive global offset
        off[m * Nn + i] = g;
        cur[m * Nn + i] = g;
        inv[m * Nn + i] = 1.0f / fmaxf((float)c, 1.0f);
    }
}

__global__ __launch_bounds__(256) void k_fill(const int* __restrict__ ei, int* __restrict__ cur,
                                              int* __restrict__ esrc) {
    int idx = blockIdx.x * 256 + threadIdx.x;
    if (idx >= METAc * Ee) return;
    int m = idx / Ee, e = idx - m * Ee;
    const int* eim = ei + (size_t)m * 2 * Ee;
    int s = eim[e], d = eim[Ee + e];
    int pos = atomicAdd(cur + m * Nn + d, 1);
    esrc[(size_t)m * Ee + pos] = s;
}

// ============ CSR aggregation: one wave per dst node, writes SUM ============
__global__ __launch_bounds__(256) void k_aggregate(const float* __restrict__ feat,
                                                   const int* __restrict__ off,
                                                   const int* __restrict__ cnt,
                                                   const int* __restrict__ esrc,
                                                   float* __restrict__ agg) {
    int gwid = (blockIdx.x * 256 + threadIdx.x) >> 6;
    if (gwid >= METAc * Nn) return;
    int m = gwid / Nn, n = gwid - m * Nn;
    int lane = threadIdx.x & 63;
    int start = off[m * Nn + n];
    int c = cnt[m * Nn + n];
    const int* es = esrc + (size_t)m * Ee;
    const float* fm = feat + (size_t)m * Nn * 128;
    float ax = 0.0f, ay = 0.0f;
    for (int e = 0; e < c; e++) {
        int s = es[start + e];
        float2 v = *(const float2*)(fm + (size_t)s * 128 + lane * 2);
        ax += v.x; ay += v.y;
    }
    float2* p = (float2*)(agg + ((size_t)m * Nn + n) * 128 + lane * 2);
    *p = make_float2(ax, ay);
}

// ================= fallback (round-0) atomic path =================
__global__ __launch_bounds__(256) void k_degree(const int* __restrict__ ei, float* __restrict__ deg) {
    int idx = blockIdx.x * 256 + threadIdx.x;
    if (idx >= METAc * Ee) return;
    int m = idx / Ee, e = idx - m * Ee;
    int dst = ei[(size_t)m * 2 * Ee + Ee + e];
    atomicAdd(deg + m * Nn + dst, 1.0f);
}

__global__ __launch_bounds__(256) void k_invdeg(float* deg) {
    int idx = blockIdx.x * 256 + threadIdx.x;
    if (idx >= METAc * Nn) return;
    deg[idx] = 1.0f / fmaxf(deg[idx], 1.0f);
}

__global__ __launch_bounds__(256) void k_scatter(const float* __restrict__ src_feat,
                                                 const int* __restrict__ ei,
                                                 float* __restrict__ agg) {
    int idx = blockIdx.x * 256 + threadIdx.x;
    if (idx >= METAc * Ee * 32) return;
    int c4 = idx & 31;
    int eg = idx >> 5;
    int m = eg / Ee, e = eg - m * Ee;
    const int* eim = ei + (size_t)m * 2 * Ee;
    int s = eim[e], d = eim[Ee + e];
    const float4 v = *(const float4*)(src_feat + ((size_t)m * Nn + s) * 128 + c4 * 4);
    float* a = agg + ((size_t)m * Nn + d) * 128 + c4 * 4;
    atomicAdd(a + 0, v.x);
    atomicAdd(a + 1, v.y);
    atomicAdd(a + 2, v.z);
    atomicAdd(a + 3, v.w);
}

// ---------------- GEMM1: h = ELU([mean,x] @ [W1l;W1r] + b1), cols=128 ----------------
__global__ __launch_bounds__(256) void k_gemm1(
    const float* __restrict__ agg, const float* __restrict__ x,
    const float* __restrict__ invdeg,
    const float* __restrict__ W1l, const float* __restrict__ W1r,
    const float* __restrict__ b1, float* __restrict__ h)
{
    const int m = blockIdx.y;
    const int row0 = blockIdx.x * 64;
    const int tid = threadIdx.x;
    const int tx = tid & 15, ty = tid >> 4;

    __shared__ float As[64][68];
    __shared__ float Ws[64][128];
    __shared__ float inv_s[64];

    if (tid < 64) {
        int r = row0 + tid;
        inv_s[tid] = (r < Nn) ? invdeg[m * Nn + r] : 0.0f;
    }

    float acc[4][8];
    #pragma unroll
    for (int i = 0; i < 4; i++)
        #pragma unroll
        for (int j = 0; j < 8; j++) acc[i][j] = 0.0f;

    const float* Asrc0 = agg + (size_t)m * Nn * 128;
    const float* Asrc1 = x   + (size_t)m * Nn * 128;
    const float* Wsrc0 = W1l + (size_t)m * 128 * 128;
    const float* Wsrc1 = W1r + (size_t)m * 128 * 128;

    for (int kk = 0; kk < 256; kk += 64) {
        __syncthreads();
        const bool first = kk < 128;
        const int kbase = first ? kk : kk - 128;
        #pragma unroll
        for (int i = 0; i < 4; i++) {
            int f4 = tid + i * 256;
            int row = f4 >> 4;
            int col4 = f4 & 15;
            int grow = row0 + row;
            int gr = grow < Nn ? grow : Nn - 1;
            const float* p = (first ? Asrc0 : Asrc1) + (size_t)gr * 128 + kbase + col4 * 4;
            float4 v = *(const float4*)p;
            if (first) { float s = inv_s[row]; v.x *= s; v.y *= s; v.z *= s; v.w *= s; }
            *(float4*)&As[row][col4 * 4] = v;
        }
        #pragma unroll
        for (int i = 0; i < 8; i++) {
            int f4 = tid + i * 256;
            int row = f4 >> 5;
            int col4 = f4 & 31;
            const float* p = (first ? Wsrc0 : Wsrc1) + (size_t)(kbase + row) * 128 + col4 * 4;
            *(float4*)&Ws[row][col4 * 4] = *(const float4*)p;
        }
        __syncthreads();
        #pragma unroll
        for (int k = 0; k < 64; k++) {
            float a[4];
            #pragma unroll
            for (int r = 0; r < 4; r++) a[r] = As[ty * 4 + r][k];
            float4 w0 = *(const float4*)&Ws[k][tx * 8];
            float4 w1 = *(const float4*)&Ws[k][tx * 8 + 4];
            float w[8] = {w0.x, w0.y, w0.z, w0.w, w1.x, w1.y, w1.z, w1.w};
            #pragma unroll
            for (int r = 0; r < 4; r++)
                #pragma unroll
                for (int c = 0; c < 8; c++)
                    acc[r][c] += a[r] * w[c];
        }
    }

    const int j0 = tx * 8;
    float bias[8];
    #pragma unroll
    for (int c = 0; c < 8; c++) bias[c] = b1[m * 128 + j0 + c];
    #pragma unroll
    for (int r = 0; r < 4; r++) {
        int grow = row0 + ty * 4 + r;
        if (grow >= Nn) continue;
        float o[8];
        #pragma unroll
        for (int c = 0; c < 8; c++) {
            float v = acc[r][c] + bias[c];
            o[c] = v > 0.0f ? v : expm1f(v);
        }
        float4* p = (float4*)(h + ((size_t)m * Nn + grow) * 128 + j0);
        p[0] = make_float4(o[0], o[1], o[2], o[3]);
        p[1] = make_float4(o[4], o[5], o[6], o[7]);
    }
}

// ---------------- GEMM2: out = log_softmax([mean,h] @ [W2l;W2r] + b2), cols=64 ----------------
__global__ __launch_bounds__(256) void k_gemm2(
    const float* __restrict__ agg, const float* __restrict__ h,
    const float* __restrict__ invdeg,
    const float* __restrict__ W2l, const float* __restrict__ W2r,
    const float* __restrict__ b2, float* __restrict__ out)
{
    const int m = blockIdx.y;
    const int row0 = blockIdx.x * 64;
    const int tid = threadIdx.x;
    const int tx = tid & 15, ty = tid >> 4;

    __shared__ float As[64][68];
    __shared__ float Ws[64][64];
    __shared__ float inv_s[64];

    if (tid < 64) {
        int r = row0 + tid;
        inv_s[tid] = (r < Nn) ? invdeg[m * Nn + r] : 0.0f;
    }

    float acc[4][4];
    #pragma unroll
    for (int i = 0; i < 4; i++)
        #pragma unroll
        for (int j = 0; j < 4; j++) acc[i][j] = 0.0f;

    const float* Asrc0 = agg + (size_t)m * Nn * 128;
    const float* Asrc1 = h   + (size_t)m * Nn * 128;
    const float* Wsrc0 = W2l + (size_t)m * 128 * 64;
    const float* Wsrc1 = W2r + (size_t)m * 128 * 64;

    for (int kk = 0; kk < 256; kk += 64) {
        __syncthreads();
        const bool first = kk < 128;
        const int kbase = first ? kk : kk - 128;
        #pragma unroll
        for (int i = 0; i < 4; i++) {
            int f4 = tid + i * 256;
            int row = f4 >> 4;
            int col4 = f4 & 15;
            int grow = row0 + row;
            int gr = grow < Nn ? grow : Nn - 1;
            const float* p = (first ? Asrc0 : Asrc1) + (size_t)gr * 128 + kbase + col4 * 4;
            float4 v = *(const float4*)p;
            if (first) { float s = inv_s[row]; v.x *= s; v.y *= s; v.z *= s; v.w *= s; }
            *(float4*)&As[row][col4 * 4] = v;
        }
        #pragma unroll
        for (int i = 0; i < 4; i++) {
            int f4 = tid + i * 256;
            int row = f4 >> 4;
            int col4 = f4 & 15;
            const float* p = (first ? Wsrc0 : Wsrc1) + (size_t)(kbase + row) * 64 + col4 * 4;
            *(float4*)&Ws[row][col4 * 4] = *(const float4*)p;
        }
        __syncthreads();
        #pragma unroll
        for (int k = 0; k < 64; k++) {
            float a[4];
            #pragma unroll
            for (int r = 0; r < 4; r++) a[r] = As[ty * 4 + r][k];
            float4 w = *(const float4*)&Ws[k][tx * 4];
            float wv[4] = {w.x, w.y, w.z, w.w};
            #pragma unroll
            for (int r = 0; r < 4; r++)
                #pragma unroll
                for (int c = 0; c < 4; c++)
                    acc[r][c] += a[r] * wv[c];
        }
    }

    const int j0 = tx * 4;
    float bias[4];
    #pragma unroll
    for (int c = 0; c < 4; c++) bias[c] = b2[m * 64 + j0 + c];

    #pragma unroll
    for (int r = 0; r < 4; r++) {
        int grow = row0 + ty * 4 + r;
        float z[4];
        #pragma unroll
        for (int c = 0; c < 4; c++) z[c] = acc[r][c] + bias[c];
        float mx = fmaxf(fmaxf(z[0], z[1]), fmaxf(z[2], z[3]));
        #pragma unroll
        for (int mask = 1; mask <= 8; mask <<= 1)
            mx = fmaxf(mx, __shfl_xor(mx, mask));
        float s = 0.0f;
        #pragma unroll
        for (int c = 0; c < 4; c++) s += expf(z[c] - mx);
        #pragma unroll
        for (int mask = 1; mask <= 8; mask <<= 1)
            s += __shfl_xor(s, mask);
        float lse = mx + logf(s);
        if (grow < Nn) {
            float4 o = make_float4(z[0] - lse, z[1] - lse, z[2] - lse, z[3] - lse);
            *(float4*)(out + ((size_t)m * Nn + grow) * 64 + j0) = o;
        }
    }
}

extern "C" void kernel_launch(void* const* d_in, const int* in_sizes, int n_in,
                              void* d_out, int out_size, void* d_ws, size_t ws_size,
                              hipStream_t stream) {
    const float* meta_x = (const float*)d_in[0];
    const int*   ei     = (const int*)d_in[1];
    const float* W1l    = (const float*)d_in[2];
    const float* W1r    = (const float*)d_in[3];
    const float* b1     = (const float*)d_in[4];
    const float* W2l    = (const float*)d_in[5];
    const float* W2r    = (const float*)d_in[6];
    const float* b2     = (const float*)d_in[7];
    float* out = (float*)d_out;

    const size_t nN = (size_t)METAc * Nn;
    const size_t need = nN * 4 * 4         // inv, cnt, off, cur
                      + 64 * METAc * 4     // csum
                      + (size_t)METAc * Ee * 4
                      + 2 * nN * 128 * 4;  // agg, h

    if (ws_size >= need) {
        // -------- CSR path --------
        float* inv  = (float*)d_ws;
        int*   cnt  = (int*)(inv + nN);
        int*   off  = cnt + nN;
        int*   cur  = off + nN;
        int*   csum = cur + nN;
        int*   esrc = csum + 64 * METAc;
        float* agg  = (float*)(esrc + (size_t)METAc * Ee);
        float* h    = agg + nN * 128;

        hipMemsetAsync(cnt, 0, nN * sizeof(int), stream);
        k_count<<<(METAc * Ee + 255) / 256, 256, 0, stream>>>(ei, cnt);
        k_chunksum<<<METAc * NCH, 1024, 0, stream>>>(cnt, csum);
        k_chunkscan<<<1, 256, 0, stream>>>(csum);
        k_scan<<<METAc * NCH, 1024, 0, stream>>>(cnt, csum, off, cur, inv);
        k_fill<<<(METAc * Ee + 255) / 256, 256, 0, stream>>>(ei, cur, esrc);

        k_aggregate<<<(METAc * Nn * 64 + 255) / 256, 256, 0, stream>>>(meta_x, off, cnt, esrc, agg);
        k_gemm1<<<dim3((Nn + 63) / 64, METAc), 256, 0, stream>>>(agg, meta_x, inv, W1l, W1r, b1, h);
        k_aggregate<<<(METAc * Nn * 64 + 255) / 256, 256, 0, stream>>>(h, off, cnt, esrc, agg);
        k_gemm2<<<dim3((Nn + 63) / 64, METAc), 256, 0, stream>>>(agg, h, inv, W2l, W2r, b2, out);
    } else {
        // -------- fallback: round-0 atomic path --------
        float* deg = (float*)d_ws;
        float* agg = deg + nN;
        float* h   = agg + nN * 128;

        hipMemsetAsync(deg, 0, nN * sizeof(float), stream);
        hipMemsetAsync(agg, 0, nN * 128 * sizeof(float), stream);

        k_degree<<<(METAc * Ee + 255) / 256, 256, 0, stream>>>(ei, deg);
        k_invdeg<<<(METAc * Nn + 255) / 256, 256, 0, stream>>>(deg);
        k_scatter<<<(METAc * Ee * 32 + 255) / 256, 256, 0, stream>>>(meta_x, ei, agg);
        k_gemm1<<<dim3((Nn + 63) / 64, METAc), 256, 0, stream>>>(agg, meta_x, deg, W1l, W1r, b1, h);
        hipMemsetAsync(agg, 0, nN * 128 * sizeof(float), stream);
        k_scatter<<<(METAc * Ee * 32 + 255) / 256, 256, 0, stream>>>(h, ei, agg);
        k_gemm2<<<dim3((Nn + 63) / 64, METAc), 256, 0, stream>>>(agg, h, deg, W2l, W2r, b2, out);
    }
}

// Round 3
// 697.317 us; speedup vs baseline: 9.7121x; 1.2648x over previous
//
#include <hip/hip_runtime.h>

#define METAc 3
#define Nn 50000
#define Ee 640000
#define CHUNK 1024
#define NCH 49   // ceil(Nn/CHUNK)

typedef unsigned int uint;
typedef unsigned short ushort;

__device__ __forceinline__ float bf2f(uint u16) {
    union { uint u; float f; } v; v.u = u16 << 16; return v.f;
}
__device__ __forceinline__ uint f2bf(float f) {
    union { float f; uint u; } v; v.f = f;
    return (v.u + 0x7fffu + ((v.u >> 16) & 1u)) >> 16;
}

// ================= CSR build =================
__global__ __launch_bounds__(256) void k_count(const int* __restrict__ ei, int* __restrict__ cnt) {
    int idx = blockIdx.x * 256 + threadIdx.x;
    if (idx >= METAc * Ee) return;
    int m = idx / Ee, e = idx - m * Ee;
    int dst = ei[(size_t)m * 2 * Ee + Ee + e];
    atomicAdd(cnt + m * Nn + dst, 1);
}

__global__ __launch_bounds__(1024) void k_chunksum(const int* __restrict__ cnt, int* __restrict__ csum) {
    int m = blockIdx.x / NCH, ch = blockIdx.x - m * NCH;
    int tid = threadIdx.x;
    int i = ch * CHUNK + tid;
    int v = (i < Nn) ? cnt[m * Nn + i] : 0;
    #pragma unroll
    for (int o = 1; o < 64; o <<= 1) v += __shfl_xor(v, o);
    __shared__ int ws_[16];
    int lane = tid & 63, w = tid >> 6;
    if (lane == 0) ws_[w] = v;
    __syncthreads();
    if (tid == 0) {
        int s = 0;
        #pragma unroll
        for (int k = 0; k < 16; k++) s += ws_[k];
        csum[m * 64 + ch] = s;
    }
}

__global__ __launch_bounds__(256) void k_chunkscan(int* __restrict__ csum) {
    int tid = threadIdx.x;
    int w = tid >> 6, lane = tid & 63;
    if (w >= METAc) return;
    int v = (lane < NCH) ? csum[w * 64 + lane] : 0;
    int orig = v;
    #pragma unroll
    for (int o = 1; o < 64; o <<= 1) { int t = __shfl_up(v, o); if (lane >= o) v += t; }
    if (lane < NCH) csum[w * 64 + lane] = v - orig;
}

__global__ __launch_bounds__(1024) void k_scan(const int* __restrict__ cnt, const int* __restrict__ csum,
                                               int* __restrict__ off, int* __restrict__ cur,
                                               float* __restrict__ inv) {
    int m = blockIdx.x / NCH, ch = blockIdx.x - m * NCH;
    int tid = threadIdx.x;
    int i = ch * CHUNK + tid;
    int c = (i < Nn) ? cnt[m * Nn + i] : 0;
    int lane = tid & 63, w = tid >> 6;
    int v = c;
    #pragma unroll
    for (int o = 1; o < 64; o <<= 1) { int t = __shfl_up(v, o); if (lane >= o) v += t; }
    __shared__ int ws_[16];
    if (lane == 63) ws_[w] = v;
    __syncthreads();
    if (tid < 16) {
        int s = ws_[tid];
        #pragma unroll
        for (int o = 1; o < 16; o <<= 1) { int t = __shfl_up(s, o); if (lane >= o) s += t; }
        ws_[tid] = s;
    }
    __syncthreads();
    int base = (w > 0) ? ws_[w - 1] : 0;
    if (i < Nn) {
        int g = csum[m * 64 + ch] + base + v - c;
        off[m * Nn + i] = g;
        cur[m * Nn + i] = g;
        inv[m * Nn + i] = 1.0f / fmaxf((float)c, 1.0f);
    }
}

__global__ __launch_bounds__(256) void k_fill(const int* __restrict__ ei, int* __restrict__ cur,
                                              int* __restrict__ esrc) {
    int idx = blockIdx.x * 256 + threadIdx.x;
    if (idx >= METAc * Ee) return;
    int m = idx / Ee, e = idx - m * Ee;
    const int* eim = ei + (size_t)m * 2 * Ee;
    int s = eim[e], d = eim[Ee + e];
    int pos = atomicAdd(cur + m * Nn + d, 1);
    esrc[(size_t)m * Ee + pos] = s;
}

// ============ xform1: t1/r1 = x @ (W1l|W1r) (+b1 on z==1), bf16 out ============
__global__ __launch_bounds__(256) void k_xform1(
    const float* __restrict__ x, const float* __restrict__ W1l, const float* __restrict__ W1r,
    const float* __restrict__ b1, ushort* __restrict__ t1, ushort* __restrict__ r1)
{
    const int m = blockIdx.y;
    const int zz = blockIdx.z;
    const int row0 = blockIdx.x * 64;
    const int tid = threadIdx.x;
    const int tx = tid & 15, ty = tid >> 4;

    const float* A = x + (size_t)m * Nn * 128;
    const float* W = (zz ? W1r : W1l) + (size_t)m * 128 * 128;
    ushort* outp = (zz ? r1 : t1) + (size_t)m * Nn * 128;

    __shared__ float As[64][68];
    __shared__ float Ws[64][128];

    float acc[4][8];
    #pragma unroll
    for (int i = 0; i < 4; i++)
        #pragma unroll
        for (int j = 0; j < 8; j++) acc[i][j] = 0.0f;

    for (int kk = 0; kk < 128; kk += 64) {
        __syncthreads();
        #pragma unroll
        for (int i = 0; i < 4; i++) {
            int f4 = tid + i * 256;
            int row = f4 >> 4;
            int col4 = f4 & 15;
            int grow = row0 + row;
            int gr = grow < Nn ? grow : Nn - 1;
            float4 v = *(const float4*)(A + (size_t)gr * 128 + kk + col4 * 4);
            *(float4*)&As[row][col4 * 4] = v;
        }
        #pragma unroll
        for (int i = 0; i < 8; i++) {
            int f4 = tid + i * 256;
            int row = f4 >> 5;
            int col4 = f4 & 31;
            *(float4*)&Ws[row][col4 * 4] = *(const float4*)(W + (size_t)(kk + row) * 128 + col4 * 4);
        }
        __syncthreads();
        #pragma unroll
        for (int k = 0; k < 64; k++) {
            float a[4];
            #pragma unroll
            for (int r = 0; r < 4; r++) a[r] = As[ty * 4 + r][k];
            float4 w0 = *(const float4*)&Ws[k][tx * 8];
            float4 w1 = *(const float4*)&Ws[k][tx * 8 + 4];
            float w[8] = {w0.x, w0.y, w0.z, w0.w, w1.x, w1.y, w1.z, w1.w};
            #pragma unroll
            for (int r = 0; r < 4; r++)
                #pragma unroll
                for (int c = 0; c < 8; c++)
                    acc[r][c] += a[r] * w[c];
        }
    }

    const int j0 = tx * 8;
    float bias[8];
    #pragma unroll
    for (int c = 0; c < 8; c++) bias[c] = zz ? b1[m * 128 + j0 + c] : 0.0f;
    #pragma unroll
    for (int r = 0; r < 4; r++) {
        int grow = row0 + ty * 4 + r;
        if (grow >= Nn) continue;
        uint o[4];
        #pragma unroll
        for (int c = 0; c < 4; c++) {
            float v0 = acc[r][2 * c] + bias[2 * c];
            float v1 = acc[r][2 * c + 1] + bias[2 * c + 1];
            o[c] = f2bf(v0) | (f2bf(v1) << 16);
        }
        *(uint4*)(outp + (size_t)grow * 128 + j0) = make_uint4(o[0], o[1], o[2], o[3]);
    }
}

// ============ agg1: h = ELU(mean-gather(t1) + r1), bf16 ============
__global__ __launch_bounds__(256) void k_agg_elu(
    const ushort* __restrict__ t1, const ushort* __restrict__ r1,
    const int* __restrict__ off, const int* __restrict__ cnt,
    const float* __restrict__ inv, const int* __restrict__ esrc,
    ushort* __restrict__ h)
{
    int gwid = (blockIdx.x * 256 + threadIdx.x) >> 6;
    if (gwid >= METAc * Nn) return;
    int m = gwid / Nn, n = gwid - m * Nn;
    int lane = threadIdx.x & 63;
    int start = off[m * Nn + n];
    int c = cnt[m * Nn + n];
    const int* es = esrc + (size_t)m * Ee;
    const ushort* tm = t1 + (size_t)m * Nn * 128;
    float a0 = 0.0f, a1 = 0.0f;
    int e = 0;
    for (; e + 1 < c; e += 2) {
        int s0 = es[start + e], s1 = es[start + e + 1];
        uint v0 = *(const uint*)(tm + (size_t)s0 * 128 + lane * 2);
        uint v1 = *(const uint*)(tm + (size_t)s1 * 128 + lane * 2);
        a0 += bf2f(v0 & 0xffffu) + bf2f(v1 & 0xffffu);
        a1 += bf2f(v0 >> 16) + bf2f(v1 >> 16);
    }
    if (e < c) {
        int s0 = es[start + e];
        uint v0 = *(const uint*)(tm + (size_t)s0 * 128 + lane * 2);
        a0 += bf2f(v0 & 0xffffu);
        a1 += bf2f(v0 >> 16);
    }
    float iv = inv[m * Nn + n];
    uint rv = *(const uint*)(r1 + ((size_t)m * Nn + n) * 128 + lane * 2);
    float z0 = a0 * iv + bf2f(rv & 0xffffu);
    float z1 = a1 * iv + bf2f(rv >> 16);
    z0 = z0 > 0.0f ? z0 : expm1f(z0);
    z1 = z1 > 0.0f ? z1 : expm1f(z1);
    *(uint*)(h + ((size_t)m * Nn + n) * 128 + lane * 2) = f2bf(z0) | (f2bf(z1) << 16);
}

// ============ xform2: t2/r2 = h @ (W2l|W2r) (+b2 on z==1), bf16 out ============
__global__ __launch_bounds__(256) void k_xform2(
    const ushort* __restrict__ h, const float* __restrict__ W2l, const float* __restrict__ W2r,
    const float* __restrict__ b2, ushort* __restrict__ t2, ushort* __restrict__ r2)
{
    const int m = blockIdx.y;
    const int zz = blockIdx.z;
    const int row0 = blockIdx.x * 64;
    const int tid = threadIdx.x;
    const int tx = tid & 15, ty = tid >> 4;

    const ushort* A = h + (size_t)m * Nn * 128;
    const float* W = (zz ? W2r : W2l) + (size_t)m * 128 * 64;
    ushort* outp = (zz ? r2 : t2) + (size_t)m * Nn * 64;

    __shared__ float As[64][68];
    __shared__ float Ws[64][64];

    float acc[4][4];
    #pragma unroll
    for (int i = 0; i < 4; i++)
        #pragma unroll
        for (int j = 0; j < 4; j++) acc[i][j] = 0.0f;

    for (int kk = 0; kk < 128; kk += 64) {
        __syncthreads();
        #pragma unroll
        for (int i = 0; i < 4; i++) {
            int f4 = tid + i * 256;
            int row = f4 >> 4;
            int col4 = f4 & 15;
            int grow = row0 + row;
            int gr = grow < Nn ? grow : Nn - 1;
            ushort4 v = *(const ushort4*)(A + (size_t)gr * 128 + kk + col4 * 4);
            As[row][col4 * 4 + 0] = bf2f(v.x);
            As[row][col4 * 4 + 1] = bf2f(v.y);
            As[row][col4 * 4 + 2] = bf2f(v.z);
            As[row][col4 * 4 + 3] = bf2f(v.w);
        }
        #pragma unroll
        for (int i = 0; i < 4; i++) {
            int f4 = tid + i * 256;
            int row = f4 >> 4;
            int col4 = f4 & 15;
            *(float4*)&Ws[row][col4 * 4] = *(const float4*)(W + (size_t)(kk + row) * 64 + col4 * 4);
        }
        __syncthreads();
        #pragma unroll
        for (int k = 0; k < 64; k++) {
            float a[4];
            #pragma unroll
            for (int r = 0; r < 4; r++) a[r] = As[ty * 4 + r][k];
            float4 w = *(const float4*)&Ws[k][tx * 4];
            float wv[4] = {w.x, w.y, w.z, w.w};
            #pragma unroll
            for (int r = 0; r < 4; r++)
                #pragma unroll
                for (int c = 0; c < 4; c++)
                    acc[r][c] += a[r] * wv[c];
        }
    }

    const int j0 = tx * 4;
    float bias[4];
    #pragma unroll
    for (int c = 0; c < 4; c++) bias[c] = zz ? b2[m * 64 + j0 + c] : 0.0f;
    #pragma unroll
    for (int r = 0; r < 4; r++) {
        int grow = row0 + ty * 4 + r;
        if (grow >= Nn) continue;
        uint o0 = f2bf(acc[r][0] + bias[0]) | (f2bf(acc[r][1] + bias[1]) << 16);
        uint o1 = f2bf(acc[r][2] + bias[2]) | (f2bf(acc[r][3] + bias[3]) << 16);
        *(uint2*)(outp + (size_t)grow * 64 + j0) = make_uint2(o0, o1);
    }
}

// ============ agg2: out = log_softmax(mean-gather(t2) + r2), fp32 ============
__global__ __launch_bounds__(256) void k_agg_lsm(
    const ushort* __restrict__ t2, const ushort* __restrict__ r2,
    const int* __restrict__ off, const int* __restrict__ cnt,
    const float* __restrict__ inv, const int* __restrict__ esrc,
    float* __restrict__ out)
{
    int gwid = (blockIdx.x * 256 + threadIdx.x) >> 6;
    if (gwid >= METAc * Nn) return;
    int m = gwid / Nn, n = gwid - m * Nn;
    int lane = threadIdx.x & 63;
    int half = lane >> 5;       // lanes 0-31: even edges, 32-63: odd edges
    int l32 = lane & 31;
    int start = off[m * Nn + n];
    int c = cnt[m * Nn + n];
    const int* es = esrc + (size_t)m * Ee;
    const ushort* tm = t2 + (size_t)m * Nn * 64;
    float a0 = 0.0f, a1 = 0.0f;
    for (int e = 0; e < c; e += 2) {
        int ee = e + half;
        if (ee < c) {
            int s = es[start + ee];
            uint v = *(const uint*)(tm + (size_t)s * 64 + l32 * 2);
            a0 += bf2f(v & 0xffffu);
            a1 += bf2f(v >> 16);
        }
    }
    a0 += __shfl_xor(a0, 32);
    a1 += __shfl_xor(a1, 32);
    float iv = inv[m * Nn + n];
    uint rv = *(const uint*)(r2 + ((size_t)m * Nn + n) * 64 + l32 * 2);
    float z0 = a0 * iv + bf2f(rv & 0xffffu);
    float z1 = a1 * iv + bf2f(rv >> 16);
    float mx = fmaxf(z0, z1);
    #pragma unroll
    for (int o = 1; o <= 16; o <<= 1) mx = fmaxf(mx, __shfl_xor(mx, o));
    float s = expf(z0 - mx) + expf(z1 - mx);
    #pragma unroll
    for (int o = 1; o <= 16; o <<= 1) s += __shfl_xor(s, o);
    float lse = mx + logf(s);
    if (half == 0) {
        *(float2*)(out + ((size_t)m * Nn + n) * 64 + l32 * 2) = make_float2(z0 - lse, z1 - lse);
    }
}

extern "C" void kernel_launch(void* const* d_in, const int* in_sizes, int n_in,
                              void* d_out, int out_size, void* d_ws, size_t ws_size,
                              hipStream_t stream) {
    const float* meta_x = (const float*)d_in[0];
    const int*   ei     = (const int*)d_in[1];
    const float* W1l    = (const float*)d_in[2];
    const float* W1r    = (const float*)d_in[3];
    const float* b1     = (const float*)d_in[4];
    const float* W2l    = (const float*)d_in[5];
    const float* W2r    = (const float*)d_in[6];
    const float* b2     = (const float*)d_in[7];
    float* out = (float*)d_out;

    const size_t nN = (size_t)METAc * Nn;

    float* inv  = (float*)d_ws;
    int*   cnt  = (int*)(inv + nN);
    int*   off  = cnt + nN;
    int*   cur  = off + nN;
    int*   csum = cur + nN;
    int*   esrc = csum + 64 * METAc;
    ushort* t1  = (ushort*)(esrc + (size_t)METAc * Ee);
    ushort* r1  = t1 + nN * 128;
    ushort* h   = r1 + nN * 128;
    ushort* t2  = h + nN * 128;
    ushort* r2  = t2 + nN * 64;

    hipMemsetAsync(cnt, 0, nN * sizeof(int), stream);
    k_count<<<(METAc * Ee + 255) / 256, 256, 0, stream>>>(ei, cnt);
    k_chunksum<<<METAc * NCH, 1024, 0, stream>>>(cnt, csum);
    k_chunkscan<<<1, 256, 0, stream>>>(csum);
    k_scan<<<METAc * NCH, 1024, 0, stream>>>(cnt, csum, off, cur, inv);
    k_fill<<<(METAc * Ee + 255) / 256, 256, 0, stream>>>(ei, cur, esrc);

    k_xform1<<<dim3((Nn + 63) / 64, METAc, 2), 256, 0, stream>>>(meta_x, W1l, W1r, b1, t1, r1);
    k_agg_elu<<<(METAc * Nn * 64 + 255) / 256, 256, 0, stream>>>(t1, r1, off, cnt, inv, esrc, h);
    k_xform2<<<dim3((Nn + 63) / 64, METAc, 2), 256, 0, stream>>>(h, W2l, W2r, b2, t2, r2);
    k_agg_lsm<<<(METAc * Nn * 64 + 255) / 256, 256, 0, stream>>>(t2, r2, off, cnt, inv, esrc, out);
}

// Round 4
// 593.200 us; speedup vs baseline: 11.4168x; 1.1755x over previous
//
#include <hip/hip_runtime.h>

#define METAc 3
#define Nn 50000
#define Ee 640000
#define CHUNK 1024
#define NCH 49   // ceil(Nn/CHUNK)

typedef unsigned int uint;
typedef unsigned short ushort;
typedef __attribute__((ext_vector_type(8))) short bf16x8;
typedef __attribute__((ext_vector_type(4))) float f32x4;

__device__ __forceinline__ float bf2f(uint u16) {
    union { uint u; float f; } v; v.u = u16 << 16; return v.f;
}
__device__ __forceinline__ uint f2bf(float f) {
    union { float f; uint u; } v; v.f = f;
    return (v.u + 0x7fffu + ((v.u >> 16) & 1u)) >> 16;
}
__device__ __forceinline__ f32x4 mfma16(bf16x8 a, bf16x8 b, f32x4 c) {
    return __builtin_amdgcn_mfma_f32_16x16x32_bf16(a, b, c, 0, 0, 0);
}

// ================= CSR build =================
__global__ __launch_bounds__(256) void k_count(const int* __restrict__ ei, int* __restrict__ cnt) {
    int idx = blockIdx.x * 256 + threadIdx.x;
    if (idx >= METAc * Ee) return;
    int m = idx / Ee, e = idx - m * Ee;
    int dst = ei[(size_t)m * 2 * Ee + Ee + e];
    atomicAdd(cnt + m * Nn + dst, 1);
}

__global__ __launch_bounds__(1024) void k_chunksum(const int* __restrict__ cnt, int* __restrict__ csum) {
    int m = blockIdx.x / NCH, ch = blockIdx.x - m * NCH;
    int tid = threadIdx.x;
    int i = ch * CHUNK + tid;
    int v = (i < Nn) ? cnt[m * Nn + i] : 0;
    #pragma unroll
    for (int o = 1; o < 64; o <<= 1) v += __shfl_xor(v, o);
    __shared__ int ws_[16];
    int lane = tid & 63, w = tid >> 6;
    if (lane == 0) ws_[w] = v;
    __syncthreads();
    if (tid == 0) {
        int s = 0;
        #pragma unroll
        for (int k = 0; k < 16; k++) s += ws_[k];
        csum[m * 64 + ch] = s;
    }
}

__global__ __launch_bounds__(256) void k_chunkscan(int* __restrict__ csum) {
    int tid = threadIdx.x;
    int w = tid >> 6, lane = tid & 63;
    if (w >= METAc) return;
    int v = (lane < NCH) ? csum[w * 64 + lane] : 0;
    int orig = v;
    #pragma unroll
    for (int o = 1; o < 64; o <<= 1) { int t = __shfl_up(v, o); if (lane >= o) v += t; }
    if (lane < NCH) csum[w * 64 + lane] = v - orig;
}

__global__ __launch_bounds__(1024) void k_scan(const int* __restrict__ cnt, const int* __restrict__ csum,
                                               int* __restrict__ off, int* __restrict__ cur,
                                               float* __restrict__ inv) {
    int m = blockIdx.x / NCH, ch = blockIdx.x - m * NCH;
    int tid = threadIdx.x;
    int i = ch * CHUNK + tid;
    int c = (i < Nn) ? cnt[m * Nn + i] : 0;
    int lane = tid & 63, w = tid >> 6;
    int v = c;
    #pragma unroll
    for (int o = 1; o < 64; o <<= 1) { int t = __shfl_up(v, o); if (lane >= o) v += t; }
    __shared__ int ws_[16];
    if (lane == 63) ws_[w] = v;
    __syncthreads();
    if (tid < 16) {
        int s = ws_[tid];
        #pragma unroll
        for (int o = 1; o < 16; o <<= 1) { int t = __shfl_up(s, o); if (lane >= o) s += t; }
        ws_[tid] = s;
    }
    __syncthreads();
    int base = (w > 0) ? ws_[w - 1] : 0;
    if (i < Nn) {
        int g = csum[m * 64 + ch] + base + v - c;
        off[m * Nn + i] = g;
        cur[m * Nn + i] = g;
        inv[m * Nn + i] = 1.0f / fmaxf((float)c, 1.0f);
    }
}

__global__ __launch_bounds__(256) void k_fill(const int* __restrict__ ei, int* __restrict__ cur,
                                              int* __restrict__ esrc) {
    int idx = blockIdx.x * 256 + threadIdx.x;
    if (idx >= METAc * Ee) return;
    int m = idx / Ee, e = idx - m * Ee;
    const int* eim = ei + (size_t)m * 2 * Ee;
    int s = eim[e], d = eim[Ee + e];
    int pos = atomicAdd(cur + m * Nn + d, 1);
    esrc[(size_t)m * Ee + pos] = s;
}

// ============ weight prep: Wcat1[m][j][k] (j<128: W1l col j, else W1r), Wcat2[m][j][k] ============
__global__ __launch_bounds__(256) void k_wcat(
    const float* __restrict__ W1l, const float* __restrict__ W1r,
    const float* __restrict__ W2l, const float* __restrict__ W2r,
    ushort* __restrict__ Wcat1, ushort* __restrict__ Wcat2)
{
    int idx = blockIdx.x * 256 + threadIdx.x;
    if (idx >= METAc * 384 * 128) return;
    int m = idx / (384 * 128);
    int rem = idx - m * 384 * 128;
    int j = rem >> 7;
    int k = rem & 127;
    if (j < 256) {
        float v = (j < 128) ? W1l[((size_t)m * 128 + k) * 128 + j]
                            : W1r[((size_t)m * 128 + k) * 128 + (j - 128)];
        Wcat1[((size_t)m * 256 + j) * 128 + k] = (ushort)f2bf(v);
    } else {
        int j2 = j - 256;
        float v = (j2 < 64) ? W2l[((size_t)m * 128 + k) * 64 + j2]
                            : W2r[((size_t)m * 128 + k) * 64 + (j2 - 64)];
        Wcat2[((size_t)m * 128 + j2) * 128 + k] = (ushort)f2bf(v);
    }
}

// ============ MFMA GEMM1: t1/r1 = x @ W1{l,r} (+b1 on z==1), bf16 out ============
__global__ __launch_bounds__(256) void k_mfma1(
    const float* __restrict__ x, const ushort* __restrict__ Wcat1,
    const float* __restrict__ b1, ushort* __restrict__ t1, ushort* __restrict__ r1)
{
    const int m = blockIdx.y, z = blockIdx.z;
    const int row0 = blockIdx.x * 128;
    const int tid = threadIdx.x;
    const int lane = tid & 63, w = tid >> 6;
    const int wr = w >> 1, wc = w & 1;

    __shared__ ushort As[128][136];   // 272B rows: 2-way bank aliasing only
    __shared__ ushort Bs[128][136];

    const float* Am = x + (size_t)m * Nn * 128;
    const ushort* Bm = Wcat1 + ((size_t)m * 256 + (size_t)z * 128) * 128;

    // stage A (fp32 -> bf16): 128 rows x 32 float4
    #pragma unroll
    for (int i = 0; i < 16; i++) {
        int f4 = tid + i * 256;
        int row = f4 >> 5, c4 = f4 & 31;
        int gr = row0 + row; if (gr >= Nn) gr = Nn - 1;
        float4 v = *(const float4*)(Am + (size_t)gr * 128 + c4 * 4);
        uint lo = f2bf(v.x) | (f2bf(v.y) << 16);
        uint hi = f2bf(v.z) | (f2bf(v.w) << 16);
        *(uint2*)&As[row][c4 * 4] = make_uint2(lo, hi);
    }
    // stage B: 128 rows x 16 x ushort8
    #pragma unroll
    for (int i = 0; i < 8; i++) {
        int c8 = tid + i * 256;
        int row = c8 >> 4, c = c8 & 15;
        *(bf16x8*)&Bs[row][c * 8] = *(const bf16x8*)(Bm + (size_t)row * 128 + c * 8);
    }
    __syncthreads();

    f32x4 acc[4][4];
    #pragma unroll
    for (int i = 0; i < 4; i++)
        #pragma unroll
        for (int j = 0; j < 4; j++) acc[i][j] = (f32x4){0.f, 0.f, 0.f, 0.f};

    #pragma unroll
    for (int ks = 0; ks < 4; ks++) {
        bf16x8 a[4], b[4];
        #pragma unroll
        for (int i = 0; i < 4; i++)
            a[i] = *(const bf16x8*)&As[wr * 64 + i * 16 + (lane & 15)][ks * 32 + (lane >> 4) * 8];
        #pragma unroll
        for (int j = 0; j < 4; j++)
            b[j] = *(const bf16x8*)&Bs[wc * 64 + j * 16 + (lane & 15)][ks * 32 + (lane >> 4) * 8];
        #pragma unroll
        for (int i = 0; i < 4; i++)
            #pragma unroll
            for (int j = 0; j < 4; j++)
                acc[i][j] = mfma16(a[i], b[j], acc[i][j]);
    }

    ushort* outp = (z ? r1 : t1) + (size_t)m * Nn * 128;
    #pragma unroll
    for (int j = 0; j < 4; j++) {
        int col = wc * 64 + j * 16 + (lane & 15);
        float bias = z ? b1[m * 128 + col] : 0.0f;
        #pragma unroll
        for (int i = 0; i < 4; i++) {
            #pragma unroll
            for (int q = 0; q < 4; q++) {
                int row = row0 + wr * 64 + i * 16 + (lane >> 4) * 4 + q;
                if (row < Nn)
                    outp[(size_t)row * 128 + col] = (ushort)f2bf(acc[i][j][q] + bias);
            }
        }
    }
}

// ============ MFMA GEMM2: t2 (cols 0-63) / r2+b2 (cols 64-127) = h @ Wcat2, bf16 out ============
__global__ __launch_bounds__(256) void k_mfma2(
    const ushort* __restrict__ h, const ushort* __restrict__ Wcat2,
    const float* __restrict__ b2, ushort* __restrict__ t2, ushort* __restrict__ r2)
{
    const int m = blockIdx.y;
    const int row0 = blockIdx.x * 128;
    const int tid = threadIdx.x;
    const int lane = tid & 63, w = tid >> 6;
    const int wr = w >> 1, wc = w & 1;

    __shared__ ushort As[128][136];
    __shared__ ushort Bs[128][136];

    const ushort* Am = h + (size_t)m * Nn * 128;
    const ushort* Bm = Wcat2 + (size_t)m * 128 * 128;

    #pragma unroll
    for (int i = 0; i < 8; i++) {
        int c8 = tid + i * 256;
        int row = c8 >> 4, c = c8 & 15;
        int gr = row0 + row; if (gr >= Nn) gr = Nn - 1;
        *(bf16x8*)&As[row][c * 8] = *(const bf16x8*)(Am + (size_t)gr * 128 + c * 8);
    }
    #pragma unroll
    for (int i = 0; i < 8; i++) {
        int c8 = tid + i * 256;
        int row = c8 >> 4, c = c8 & 15;
        *(bf16x8*)&Bs[row][c * 8] = *(const bf16x8*)(Bm + (size_t)row * 128 + c * 8);
    }
    __syncthreads();

    f32x4 acc[4][4];
    #pragma unroll
    for (int i = 0; i < 4; i++)
        #pragma unroll
        for (int j = 0; j < 4; j++) acc[i][j] = (f32x4){0.f, 0.f, 0.f, 0.f};

    #pragma unroll
    for (int ks = 0; ks < 4; ks++) {
        bf16x8 a[4], b[4];
        #pragma unroll
        for (int i = 0; i < 4; i++)
            a[i] = *(const bf16x8*)&As[wr * 64 + i * 16 + (lane & 15)][ks * 32 + (lane >> 4) * 8];
        #pragma unroll
        for (int j = 0; j < 4; j++)
            b[j] = *(const bf16x8*)&Bs[wc * 64 + j * 16 + (lane & 15)][ks * 32 + (lane >> 4) * 8];
        #pragma unroll
        for (int i = 0; i < 4; i++)
            #pragma unroll
            for (int j = 0; j < 4; j++)
                acc[i][j] = mfma16(a[i], b[j], acc[i][j]);
    }

    // wc==0 -> t2 (no bias), wc==1 -> r2 (+b2)
    ushort* outp = (wc ? r2 : t2) + (size_t)m * Nn * 64;
    #pragma unroll
    for (int j = 0; j < 4; j++) {
        int cl = j * 16 + (lane & 15);           // 0..63 within half
        float bias = wc ? b2[m * 64 + cl] : 0.0f;
        #pragma unroll
        for (int i = 0; i < 4; i++) {
            #pragma unroll
            for (int q = 0; q < 4; q++) {
                int row = row0 + wr * 64 + i * 16 + (lane >> 4) * 4 + q;
                if (row < Nn)
                    outp[(size_t)row * 64 + cl] = (ushort)f2bf(acc[i][j][q] + bias);
            }
        }
    }
}

// ============ agg1: h = ELU(mean-gather(t1) + r1), bf16 ============
__global__ __launch_bounds__(256) void k_agg_elu(
    const ushort* __restrict__ t1, const ushort* __restrict__ r1,
    const int* __restrict__ off, const int* __restrict__ cnt,
    const float* __restrict__ inv, const int* __restrict__ esrc,
    ushort* __restrict__ h)
{
    int gwid = (blockIdx.x * 256 + threadIdx.x) >> 6;
    if (gwid >= METAc * Nn) return;
    int m = gwid / Nn, n = gwid - m * Nn;
    int lane = threadIdx.x & 63;
    int start = off[m * Nn + n];
    int c = cnt[m * Nn + n];
    const int* es = esrc + (size_t)m * Ee;
    const ushort* tm = t1 + (size_t)m * Nn * 128;
    float a0 = 0.0f, a1 = 0.0f;
    int e = 0;
    for (; e + 1 < c; e += 2) {
        int s0 = es[start + e], s1 = es[start + e + 1];
        uint v0 = *(const uint*)(tm + (size_t)s0 * 128 + lane * 2);
        uint v1 = *(const uint*)(tm + (size_t)s1 * 128 + lane * 2);
        a0 += bf2f(v0 & 0xffffu) + bf2f(v1 & 0xffffu);
        a1 += bf2f(v0 >> 16) + bf2f(v1 >> 16);
    }
    if (e < c) {
        int s0 = es[start + e];
        uint v0 = *(const uint*)(tm + (size_t)s0 * 128 + lane * 2);
        a0 += bf2f(v0 & 0xffffu);
        a1 += bf2f(v0 >> 16);
    }
    float iv = inv[m * Nn + n];
    uint rv = *(const uint*)(r1 + ((size_t)m * Nn + n) * 128 + lane * 2);
    float z0 = a0 * iv + bf2f(rv & 0xffffu);
    float z1 = a1 * iv + bf2f(rv >> 16);
    z0 = z0 > 0.0f ? z0 : expm1f(z0);
    z1 = z1 > 0.0f ? z1 : expm1f(z1);
    *(uint*)(h + ((size_t)m * Nn + n) * 128 + lane * 2) = f2bf(z0) | (f2bf(z1) << 16);
}

// ============ agg2: out = log_softmax(mean-gather(t2) + r2), fp32 ============
__global__ __launch_bounds__(256) void k_agg_lsm(
    const ushort* __restrict__ t2, const ushort* __restrict__ r2,
    const int* __restrict__ off, const int* __restrict__ cnt,
    const float* __restrict__ inv, const int* __restrict__ esrc,
    float* __restrict__ out)
{
    int gwid = (blockIdx.x * 256 + threadIdx.x) >> 6;
    if (gwid >= METAc * Nn) return;
    int m = gwid / Nn, n = gwid - m * Nn;
    int lane = threadIdx.x & 63;
    int half = lane >> 5;
    int l32 = lane & 31;
    int start = off[m * Nn + n];
    int c = cnt[m * Nn + n];
    const int* es = esrc + (size_t)m * Ee;
    const ushort* tm = t2 + (size_t)m * Nn * 64;
    float a0 = 0.0f, a1 = 0.0f;
    for (int e = 0; e < c; e += 2) {
        int ee = e + half;
        if (ee < c) {
            int s = es[start + ee];
            uint v = *(const uint*)(tm + (size_t)s * 64 + l32 * 2);
            a0 += bf2f(v & 0xffffu);
            a1 += bf2f(v >> 16);
        }
    }
    a0 += __shfl_xor(a0, 32);
    a1 += __shfl_xor(a1, 32);
    float iv = inv[m * Nn + n];
    uint rv = *(const uint*)(r2 + ((size_t)m * Nn + n) * 64 + l32 * 2);
    float z0 = a0 * iv + bf2f(rv & 0xffffu);
    float z1 = a1 * iv + bf2f(rv >> 16);
    float mx = fmaxf(z0, z1);
    #pragma unroll
    for (int o = 1; o <= 16; o <<= 1) mx = fmaxf(mx, __shfl_xor(mx, o));
    float s = expf(z0 - mx) + expf(z1 - mx);
    #pragma unroll
    for (int o = 1; o <= 16; o <<= 1) s += __shfl_xor(s, o);
    float lse = mx + logf(s);
    if (half == 0) {
        *(float2*)(out + ((size_t)m * Nn + n) * 64 + l32 * 2) = make_float2(z0 - lse, z1 - lse);
    }
}

extern "C" void kernel_launch(void* const* d_in, const int* in_sizes, int n_in,
                              void* d_out, int out_size, void* d_ws, size_t ws_size,
                              hipStream_t stream) {
    const float* meta_x = (const float*)d_in[0];
    const int*   ei     = (const int*)d_in[1];
    const float* W1l    = (const float*)d_in[2];
    const float* W1r    = (const float*)d_in[3];
    const float* b1     = (const float*)d_in[4];
    const float* W2l    = (const float*)d_in[5];
    const float* W2r    = (const float*)d_in[6];
    const float* b2     = (const float*)d_in[7];
    float* out = (float*)d_out;

    const size_t nN = (size_t)METAc * Nn;

    float* inv  = (float*)d_ws;
    int*   cnt  = (int*)(inv + nN);
    int*   off  = cnt + nN;
    int*   cur  = off + nN;
    int*   csum = cur + nN;
    int*   esrc = csum + 64 * METAc;
    ushort* t1  = (ushort*)(esrc + (size_t)METAc * Ee);
    ushort* r1  = t1 + nN * 128;
    ushort* h   = r1 + nN * 128;
    ushort* t2  = h + nN * 128;
    ushort* r2  = t2 + nN * 64;
    ushort* Wcat1 = r2 + nN * 64;            // META*256*128
    ushort* Wcat2 = Wcat1 + (size_t)METAc * 256 * 128;  // META*128*128

    hipMemsetAsync(cnt, 0, nN * sizeof(int), stream);
    k_count<<<(METAc * Ee + 255) / 256, 256, 0, stream>>>(ei, cnt);
    k_chunksum<<<METAc * NCH, 1024, 0, stream>>>(cnt, csum);
    k_chunkscan<<<1, 256, 0, stream>>>(csum);
    k_scan<<<METAc * NCH, 1024, 0, stream>>>(cnt, csum, off, cur, inv);
    k_fill<<<(METAc * Ee + 255) / 256, 256, 0, stream>>>(ei, cur, esrc);
    k_wcat<<<(METAc * 384 * 128 + 255) / 256, 256, 0, stream>>>(W1l, W1r, W2l, W2r, Wcat1, Wcat2);

    k_mfma1<<<dim3((Nn + 127) / 128, METAc, 2), 256, 0, stream>>>(meta_x, Wcat1, b1, t1, r1);
    k_agg_elu<<<(METAc * Nn * 64 + 255) / 256, 256, 0, stream>>>(t1, r1, off, cnt, inv, esrc, h);
    k_mfma2<<<dim3((Nn + 127) / 128, METAc, 1), 256, 0, stream>>>(h, Wcat2, b2, t2, r2);
    k_agg_lsm<<<(METAc * Nn * 64 + 255) / 256, 256, 0, stream>>>(t2, r2, off, cnt, inv, esrc, out);
}

// Round 5
// 551.774 us; speedup vs baseline: 12.2739x; 1.0751x over previous
//
#include <hip/hip_runtime.h>

#define METAc 3
#define Nn 50000
#define Ee 640000
#define CHUNK 1024
#define NCH 49   // ceil(Nn/CHUNK)
#define NXCD 8
#define FILL_WPX 128   // workgroups per XCD-slice for k_fill2

typedef unsigned int uint;
typedef unsigned short ushort;
typedef __attribute__((ext_vector_type(8))) short bf16x8;
typedef __attribute__((ext_vector_type(4))) float f32x4;

__device__ __forceinline__ float bf2f(uint u16) {
    union { uint u; float f; } v; v.u = u16 << 16; return v.f;
}
__device__ __forceinline__ uint f2bf(float f) {
    union { float f; uint u; } v; v.f = f;
    return (v.u + 0x7fffu + ((v.u >> 16) & 1u)) >> 16;
}
__device__ __forceinline__ f32x4 mfma16(bf16x8 a, bf16x8 b, f32x4 c) {
    return __builtin_amdgcn_mfma_f32_16x16x32_bf16(a, b, c, 0, 0, 0);
}

// ================= CSR build =================
__global__ __launch_bounds__(256) void k_count(const int* __restrict__ ei, int* __restrict__ cnt) {
    int idx = blockIdx.x * 256 + threadIdx.x;
    if (idx >= METAc * Ee) return;
    int m = idx / Ee, e = idx - m * Ee;
    int dst = ei[(size_t)m * 2 * Ee + Ee + e];
    atomicAdd(cnt + m * Nn + dst, 1);
}

__global__ __launch_bounds__(1024) void k_chunksum(const int* __restrict__ cnt, int* __restrict__ csum) {
    int m = blockIdx.x / NCH, ch = blockIdx.x - m * NCH;
    int tid = threadIdx.x;
    int i = ch * CHUNK + tid;
    int v = (i < Nn) ? cnt[m * Nn + i] : 0;
    #pragma unroll
    for (int o = 1; o < 64; o <<= 1) v += __shfl_xor(v, o);
    __shared__ int ws_[16];
    int lane = tid & 63, w = tid >> 6;
    if (lane == 0) ws_[w] = v;
    __syncthreads();
    if (tid == 0) {
        int s = 0;
        #pragma unroll
        for (int k = 0; k < 16; k++) s += ws_[k];
        csum[m * 64 + ch] = s;
    }
}

__global__ __launch_bounds__(256) void k_chunkscan(int* __restrict__ csum) {
    int tid = threadIdx.x;
    int w = tid >> 6, lane = tid & 63;
    if (w >= METAc) return;
    int v = (lane < NCH) ? csum[w * 64 + lane] : 0;
    int orig = v;
    #pragma unroll
    for (int o = 1; o < 64; o <<= 1) { int t = __shfl_up(v, o); if (lane >= o) v += t; }
    if (lane < NCH) csum[w * 64 + lane] = v - orig;
}

__global__ __launch_bounds__(1024) void k_scan(const int* __restrict__ cnt, const int* __restrict__ csum,
                                               int* __restrict__ off, int* __restrict__ cur,
                                               float* __restrict__ inv) {
    int m = blockIdx.x / NCH, ch = blockIdx.x - m * NCH;
    int tid = threadIdx.x;
    int i = ch * CHUNK + tid;
    int c = (i < Nn) ? cnt[m * Nn + i] : 0;
    int lane = tid & 63, w = tid >> 6;
    int v = c;
    #pragma unroll
    for (int o = 1; o < 64; o <<= 1) { int t = __shfl_up(v, o); if (lane >= o) v += t; }
    __shared__ int ws_[16];
    if (lane == 63) ws_[w] = v;
    __syncthreads();
    if (tid < 16) {
        int s = ws_[tid];
        #pragma unroll
        for (int o = 1; o < 16; o <<= 1) { int t = __shfl_up(s, o); if (lane >= o) s += t; }
        ws_[tid] = s;
    }
    __syncthreads();
    int base = (w > 0) ? ws_[w - 1] : 0;
    if (i < Nn) {
        int g = csum[m * 64 + ch] + base + v - c;
        off[m * Nn + i] = g;
        cur[m * Nn + i] = g;
        inv[m * Nn + i] = 1.0f / fmaxf((float)c, 1.0f);
    }
}

// XCD-local CSR fill: workgroup b owns dst range [(b%8)*6250, (b%8+1)*6250).
// Every esrc cache line has a single writing XCD and stays L2-resident,
// eliminating the 16x partial-line write amplification of the naive fill.
__global__ __launch_bounds__(256) void k_fill2(const int* __restrict__ ei, int* __restrict__ cur,
                                               int* __restrict__ esrc) {
    const int xcd = blockIdx.x & (NXCD - 1);
    const int wslice = blockIdx.x >> 3;
    const int total = METAc * Ee;
    const int chunk = (total + FILL_WPX - 1) / FILL_WPX;
    const int beg = wslice * chunk;
    const int end = (beg + chunk < total) ? beg + chunk : total;
    const int lo = xcd * (Nn / NXCD);
    const int hi = lo + (Nn / NXCD);
    for (int idx = beg + threadIdx.x; idx < end; idx += 256) {
        int m = idx / Ee, e = idx - m * Ee;
        const int* eim = ei + (size_t)m * 2 * Ee;
        int d = eim[Ee + e];
        if (d >= lo && d < hi) {
            int s = eim[e];
            int pos = atomicAdd(cur + m * Nn + d, 1);
            esrc[(size_t)m * Ee + pos] = s;
        }
    }
}

// ============ weight prep: Wcat1[m][j][k] (j<128: W1l col j, else W1r), Wcat2[m][j][k] ============
__global__ __launch_bounds__(256) void k_wcat(
    const float* __restrict__ W1l, const float* __restrict__ W1r,
    const float* __restrict__ W2l, const float* __restrict__ W2r,
    ushort* __restrict__ Wcat1, ushort* __restrict__ Wcat2)
{
    int idx = blockIdx.x * 256 + threadIdx.x;
    if (idx >= METAc * 384 * 128) return;
    int m = idx / (384 * 128);
    int rem = idx - m * 384 * 128;
    int j = rem >> 7;
    int k = rem & 127;
    if (j < 256) {
        float v = (j < 128) ? W1l[((size_t)m * 128 + k) * 128 + j]
                            : W1r[((size_t)m * 128 + k) * 128 + (j - 128)];
        Wcat1[((size_t)m * 256 + j) * 128 + k] = (ushort)f2bf(v);
    } else {
        int j2 = j - 256;
        float v = (j2 < 64) ? W2l[((size_t)m * 128 + k) * 64 + j2]
                            : W2r[((size_t)m * 128 + k) * 64 + (j2 - 64)];
        Wcat2[((size_t)m * 128 + j2) * 128 + k] = (ushort)f2bf(v);
    }
}

// ============ MFMA GEMM1: t1/r1 = x @ W1{l,r} (+b1 on z==1), bf16 out ============
__global__ __launch_bounds__(256) void k_mfma1(
    const float* __restrict__ x, const ushort* __restrict__ Wcat1,
    const float* __restrict__ b1, ushort* __restrict__ t1, ushort* __restrict__ r1)
{
    const int m = blockIdx.y, z = blockIdx.z;
    const int row0 = blockIdx.x * 128;
    const int tid = threadIdx.x;
    const int lane = tid & 63, w = tid >> 6;
    const int wr = w >> 1, wc = w & 1;

    __shared__ ushort As[128][136];   // 272B rows: 2-way bank aliasing only
    __shared__ ushort Bs[128][136];

    const float* Am = x + (size_t)m * Nn * 128;
    const ushort* Bm = Wcat1 + ((size_t)m * 256 + (size_t)z * 128) * 128;

    #pragma unroll
    for (int i = 0; i < 16; i++) {
        int f4 = tid + i * 256;
        int row = f4 >> 5, c4 = f4 & 31;
        int gr = row0 + row; if (gr >= Nn) gr = Nn - 1;
        float4 v = *(const float4*)(Am + (size_t)gr * 128 + c4 * 4);
        uint lo = f2bf(v.x) | (f2bf(v.y) << 16);
        uint hi = f2bf(v.z) | (f2bf(v.w) << 16);
        *(uint2*)&As[row][c4 * 4] = make_uint2(lo, hi);
    }
    #pragma unroll
    for (int i = 0; i < 8; i++) {
        int c8 = tid + i * 256;
        int row = c8 >> 4, c = c8 & 15;
        *(bf16x8*)&Bs[row][c * 8] = *(const bf16x8*)(Bm + (size_t)row * 128 + c * 8);
    }
    __syncthreads();

    f32x4 acc[4][4];
    #pragma unroll
    for (int i = 0; i < 4; i++)
        #pragma unroll
        for (int j = 0; j < 4; j++) acc[i][j] = (f32x4){0.f, 0.f, 0.f, 0.f};

    #pragma unroll
    for (int ks = 0; ks < 4; ks++) {
        bf16x8 a[4], b[4];
        #pragma unroll
        for (int i = 0; i < 4; i++)
            a[i] = *(const bf16x8*)&As[wr * 64 + i * 16 + (lane & 15)][ks * 32 + (lane >> 4) * 8];
        #pragma unroll
        for (int j = 0; j < 4; j++)
            b[j] = *(const bf16x8*)&Bs[wc * 64 + j * 16 + (lane & 15)][ks * 32 + (lane >> 4) * 8];
        #pragma unroll
        for (int i = 0; i < 4; i++)
            #pragma unroll
            for (int j = 0; j < 4; j++)
                acc[i][j] = mfma16(a[i], b[j], acc[i][j]);
    }

    ushort* outp = (z ? r1 : t1) + (size_t)m * Nn * 128;
    #pragma unroll
    for (int j = 0; j < 4; j++) {
        int col = wc * 64 + j * 16 + (lane & 15);
        float bias = z ? b1[m * 128 + col] : 0.0f;
        #pragma unroll
        for (int i = 0; i < 4; i++) {
            #pragma unroll
            for (int q = 0; q < 4; q++) {
                int row = row0 + wr * 64 + i * 16 + (lane >> 4) * 4 + q;
                if (row < Nn)
                    outp[(size_t)row * 128 + col] = (ushort)f2bf(acc[i][j][q] + bias);
            }
        }
    }
}

// ============ MFMA GEMM2: t2 (cols 0-63) / r2+b2 (cols 64-127) = h @ Wcat2, bf16 out ============
__global__ __launch_bounds__(256) void k_mfma2(
    const ushort* __restrict__ h, const ushort* __restrict__ Wcat2,
    const float* __restrict__ b2, ushort* __restrict__ t2, ushort* __restrict__ r2)
{
    const int m = blockIdx.y;
    const int row0 = blockIdx.x * 128;
    const int tid = threadIdx.x;
    const int lane = tid & 63, w = tid >> 6;
    const int wr = w >> 1, wc = w & 1;

    __shared__ ushort As[128][136];
    __shared__ ushort Bs[128][136];

    const ushort* Am = h + (size_t)m * Nn * 128;
    const ushort* Bm = Wcat2 + (size_t)m * 128 * 128;

    #pragma unroll
    for (int i = 0; i < 8; i++) {
        int c8 = tid + i * 256;
        int row = c8 >> 4, c = c8 & 15;
        int gr = row0 + row; if (gr >= Nn) gr = Nn - 1;
        *(bf16x8*)&As[row][c * 8] = *(const bf16x8*)(Am + (size_t)gr * 128 + c * 8);
    }
    #pragma unroll
    for (int i = 0; i < 8; i++) {
        int c8 = tid + i * 256;
        int row = c8 >> 4, c = c8 & 15;
        *(bf16x8*)&Bs[row][c * 8] = *(const bf16x8*)(Bm + (size_t)row * 128 + c * 8);
    }
    __syncthreads();

    f32x4 acc[4][4];
    #pragma unroll
    for (int i = 0; i < 4; i++)
        #pragma unroll
        for (int j = 0; j < 4; j++) acc[i][j] = (f32x4){0.f, 0.f, 0.f, 0.f};

    #pragma unroll
    for (int ks = 0; ks < 4; ks++) {
        bf16x8 a[4], b[4];
        #pragma unroll
        for (int i = 0; i < 4; i++)
            a[i] = *(const bf16x8*)&As[wr * 64 + i * 16 + (lane & 15)][ks * 32 + (lane >> 4) * 8];
        #pragma unroll
        for (int j = 0; j < 4; j++)
            b[j] = *(const bf16x8*)&Bs[wc * 64 + j * 16 + (lane & 15)][ks * 32 + (lane >> 4) * 8];
        #pragma unroll
        for (int i = 0; i < 4; i++)
            #pragma unroll
            for (int j = 0; j < 4; j++)
                acc[i][j] = mfma16(a[i], b[j], acc[i][j]);
    }

    ushort* outp = (wc ? r2 : t2) + (size_t)m * Nn * 64;
    #pragma unroll
    for (int j = 0; j < 4; j++) {
        int cl = j * 16 + (lane & 15);
        float bias = wc ? b2[m * 64 + cl] : 0.0f;
        #pragma unroll
        for (int i = 0; i < 4; i++) {
            #pragma unroll
            for (int q = 0; q < 4; q++) {
                int row = row0 + wr * 64 + i * 16 + (lane >> 4) * 4 + q;
                if (row < Nn)
                    outp[(size_t)row * 64 + cl] = (ushort)f2bf(acc[i][j][q] + bias);
            }
        }
    }
}

// ============ agg1: h = ELU(mean-gather(t1) + r1), bf16 ============
__global__ __launch_bounds__(256) void k_agg_elu(
    const ushort* __restrict__ t1, const ushort* __restrict__ r1,
    const int* __restrict__ off, const int* __restrict__ cnt,
    const float* __restrict__ inv, const int* __restrict__ esrc,
    ushort* __restrict__ h)
{
    int gwid = (blockIdx.x * 256 + threadIdx.x) >> 6;
    if (gwid >= METAc * Nn) return;
    int m = gwid / Nn, n = gwid - m * Nn;
    int lane = threadIdx.x & 63;
    int start = off[m * Nn + n];
    int c = cnt[m * Nn + n];
    const int* es = esrc + (size_t)m * Ee;
    const ushort* tm = t1 + (size_t)m * Nn * 128;
    float a0 = 0.0f, a1 = 0.0f;
    int e = 0;
    for (; e + 1 < c; e += 2) {
        int s0 = es[start + e], s1 = es[start + e + 1];
        uint v0 = *(const uint*)(tm + (size_t)s0 * 128 + lane * 2);
        uint v1 = *(const uint*)(tm + (size_t)s1 * 128 + lane * 2);
        a0 += bf2f(v0 & 0xffffu) + bf2f(v1 & 0xffffu);
        a1 += bf2f(v0 >> 16) + bf2f(v1 >> 16);
    }
    if (e < c) {
        int s0 = es[start + e];
        uint v0 = *(const uint*)(tm + (size_t)s0 * 128 + lane * 2);
        a0 += bf2f(v0 & 0xffffu);
        a1 += bf2f(v0 >> 16);
    }
    float iv = inv[m * Nn + n];
    uint rv = *(const uint*)(r1 + ((size_t)m * Nn + n) * 128 + lane * 2);
    float z0 = a0 * iv + bf2f(rv & 0xffffu);
    float z1 = a1 * iv + bf2f(rv >> 16);
    z0 = z0 > 0.0f ? z0 : expm1f(z0);
    z1 = z1 > 0.0f ? z1 : expm1f(z1);
    *(uint*)(h + ((size_t)m * Nn + n) * 128 + lane * 2) = f2bf(z0) | (f2bf(z1) << 16);
}

// ============ agg2: out = log_softmax(mean-gather(t2) + r2), fp32 ============
__global__ __launch_bounds__(256) void k_agg_lsm(
    const ushort* __restrict__ t2, const ushort* __restrict__ r2,
    const int* __restrict__ off, const int* __restrict__ cnt,
    const float* __restrict__ inv, const int* __restrict__ esrc,
    float* __restrict__ out)
{
    int gwid = (blockIdx.x * 256 + threadIdx.x) >> 6;
    if (gwid >= METAc * Nn) return;
    int m = gwid / Nn, n = gwid - m * Nn;
    int lane = threadIdx.x & 63;
    int half = lane >> 5;
    int l32 = lane & 31;
    int start = off[m * Nn + n];
    int c = cnt[m * Nn + n];
    const int* es = esrc + (size_t)m * Ee;
    const ushort* tm = t2 + (size_t)m * Nn * 64;
    float a0 = 0.0f, a1 = 0.0f;
    for (int e = 0; e < c; e += 2) {
        int ee = e + half;
        if (ee < c) {
            int s = es[start + ee];
            uint v = *(const uint*)(tm + (size_t)s * 64 + l32 * 2);
            a0 += bf2f(v & 0xffffu);
            a1 += bf2f(v >> 16);
        }
    }
    a0 += __shfl_xor(a0, 32);
    a1 += __shfl_xor(a1, 32);
    float iv = inv[m * Nn + n];
    uint rv = *(const uint*)(r2 + ((size_t)m * Nn + n) * 64 + l32 * 2);
    float z0 = a0 * iv + bf2f(rv & 0xffffu);
    float z1 = a1 * iv + bf2f(rv >> 16);
    float mx = fmaxf(z0, z1);
    #pragma unroll
    for (int o = 1; o <= 16; o <<= 1) mx = fmaxf(mx, __shfl_xor(mx, o));
    float s = expf(z0 - mx) + expf(z1 - mx);
    #pragma unroll
    for (int o = 1; o <= 16; o <<= 1) s += __shfl_xor(s, o);
    float lse = mx + logf(s);
    if (half == 0) {
        *(float2*)(out + ((size_t)m * Nn + n) * 64 + l32 * 2) = make_float2(z0 - lse, z1 - lse);
    }
}

extern "C" void kernel_launch(void* const* d_in, const int* in_sizes, int n_in,
                              void* d_out, int out_size, void* d_ws, size_t ws_size,
                              hipStream_t stream) {
    const float* meta_x = (const float*)d_in[0];
    const int*   ei     = (const int*)d_in[1];
    const float* W1l    = (const float*)d_in[2];
    const float* W1r    = (const float*)d_in[3];
    const float* b1     = (const float*)d_in[4];
    const float* W2l    = (const float*)d_in[5];
    const float* W2r    = (const float*)d_in[6];
    const float* b2     = (const float*)d_in[7];
    float* out = (float*)d_out;

    const size_t nN = (size_t)METAc * Nn;

    float* inv  = (float*)d_ws;
    int*   cnt  = (int*)(inv + nN);
    int*   off  = cnt + nN;
    int*   cur  = off + nN;
    int*   csum = cur + nN;
    int*   esrc = csum + 64 * METAc;
    ushort* t1  = (ushort*)(esrc + (size_t)METAc * Ee);
    ushort* r1  = t1 + nN * 128;
    ushort* h   = r1 + nN * 128;
    ushort* t2  = h + nN * 128;
    ushort* r2  = t2 + nN * 64;
    ushort* Wcat1 = r2 + nN * 64;                       // META*256*128
    ushort* Wcat2 = Wcat1 + (size_t)METAc * 256 * 128;  // META*128*128

    hipMemsetAsync(cnt, 0, nN * sizeof(int), stream);
    k_count<<<(METAc * Ee + 255) / 256, 256, 0, stream>>>(ei, cnt);
    k_chunksum<<<METAc * NCH, 1024, 0, stream>>>(cnt, csum);
    k_chunkscan<<<1, 256, 0, stream>>>(csum);
    k_scan<<<METAc * NCH, 1024, 0, stream>>>(cnt, csum, off, cur, inv);
    k_fill2<<<NXCD * FILL_WPX, 256, 0, stream>>>(ei, cur, esrc);
    k_wcat<<<(METAc * 384 * 128 + 255) / 256, 256, 0, stream>>>(W1l, W1r, W2l, W2r, Wcat1, Wcat2);

    k_mfma1<<<dim3((Nn + 127) / 128, METAc, 2), 256, 0, stream>>>(meta_x, Wcat1, b1, t1, r1);
    k_agg_elu<<<(METAc * Nn * 64 + 255) / 256, 256, 0, stream>>>(t1, r1, off, cnt, inv, esrc, h);
    k_mfma2<<<dim3((Nn + 127) / 128, METAc, 1), 256, 0, stream>>>(h, Wcat2, b2, t2, r2);
    k_agg_lsm<<<(METAc * Nn * 64 + 255) / 256, 256, 0, stream>>>(t2, r2, off, cnt, inv, esrc, out);
}

// Round 6
// 480.928 us; speedup vs baseline: 14.0820x; 1.1473x over previous
//
#include <hip/hip_runtime.h>

#define METAc 3
#define Nn 50000
#define Ee 640000
#define CHUNK 1024
#define NCH 49   // ceil(Nn/CHUNK)
#define NXCD 8
#define FILL_WPX 128   // workgroups per XCD-slice for k_fill2

typedef unsigned int uint;
typedef unsigned short ushort;
typedef __attribute__((ext_vector_type(8))) short bf16x8;
typedef __attribute__((ext_vector_type(4))) float f32x4;

__device__ __forceinline__ float bf2f(uint u16) {
    union { uint u; float f; } v; v.u = u16 << 16; return v.f;
}
__device__ __forceinline__ uint f2bf(float f) {
    union { float f; uint u; } v; v.f = f;
    return (v.u + 0x7fffu + ((v.u >> 16) & 1u)) >> 16;
}
__device__ __forceinline__ f32x4 mfma16(bf16x8 a, bf16x8 b, f32x4 c) {
    return __builtin_amdgcn_mfma_f32_16x16x32_bf16(a, b, c, 0, 0, 0);
}

// ================= CSR build =================
__global__ __launch_bounds__(256) void k_count(const int* __restrict__ ei, int* __restrict__ cnt) {
    int idx = blockIdx.x * 256 + threadIdx.x;
    if (idx >= METAc * Ee) return;
    int m = idx / Ee, e = idx - m * Ee;
    int dst = ei[(size_t)m * 2 * Ee + Ee + e];
    atomicAdd(cnt + m * Nn + dst, 1);
}

__global__ __launch_bounds__(1024) void k_chunksum(const int* __restrict__ cnt, int* __restrict__ csum) {
    int m = blockIdx.x / NCH, ch = blockIdx.x - m * NCH;
    int tid = threadIdx.x;
    int i = ch * CHUNK + tid;
    int v = (i < Nn) ? cnt[m * Nn + i] : 0;
    #pragma unroll
    for (int o = 1; o < 64; o <<= 1) v += __shfl_xor(v, o);
    __shared__ int ws_[16];
    int lane = tid & 63, w = tid >> 6;
    if (lane == 0) ws_[w] = v;
    __syncthreads();
    if (tid == 0) {
        int s = 0;
        #pragma unroll
        for (int k = 0; k < 16; k++) s += ws_[k];
        csum[m * 64 + ch] = s;
    }
}

__global__ __launch_bounds__(256) void k_chunkscan(int* __restrict__ csum) {
    int tid = threadIdx.x;
    int w = tid >> 6, lane = tid & 63;
    if (w >= METAc) return;
    int v = (lane < NCH) ? csum[w * 64 + lane] : 0;
    int orig = v;
    #pragma unroll
    for (int o = 1; o < 64; o <<= 1) { int t = __shfl_up(v, o); if (lane >= o) v += t; }
    if (lane < NCH) csum[w * 64 + lane] = v - orig;
}

__global__ __launch_bounds__(1024) void k_scan(const int* __restrict__ cnt, const int* __restrict__ csum,
                                               int* __restrict__ off, int* __restrict__ cur,
                                               float* __restrict__ inv) {
    int m = blockIdx.x / NCH, ch = blockIdx.x - m * NCH;
    int tid = threadIdx.x;
    int i = ch * CHUNK + tid;
    int c = (i < Nn) ? cnt[m * Nn + i] : 0;
    int lane = tid & 63, w = tid >> 6;
    int v = c;
    #pragma unroll
    for (int o = 1; o < 64; o <<= 1) { int t = __shfl_up(v, o); if (lane >= o) v += t; }
    __shared__ int ws_[16];
    if (lane == 63) ws_[w] = v;
    __syncthreads();
    if (tid < 16) {
        int s = ws_[tid];
        #pragma unroll
        for (int o = 1; o < 16; o <<= 1) { int t = __shfl_up(s, o); if (lane >= o) s += t; }
        ws_[tid] = s;
    }
    __syncthreads();
    int base = (w > 0) ? ws_[w - 1] : 0;
    if (i < Nn) {
        int g = csum[m * 64 + ch] + base + v - c;
        off[m * Nn + i] = g;
        cur[m * Nn + i] = g;
        inv[m * Nn + i] = 1.0f / fmaxf((float)c, 1.0f);
    }
}

// XCD-local CSR fill: workgroup b owns dst range [(b%8)*6250, (b%8+1)*6250).
__global__ __launch_bounds__(256) void k_fill2(const int* __restrict__ ei, int* __restrict__ cur,
                                               int* __restrict__ esrc) {
    const int xcd = blockIdx.x & (NXCD - 1);
    const int wslice = blockIdx.x >> 3;
    const int total = METAc * Ee;
    const int chunk = (total + FILL_WPX - 1) / FILL_WPX;
    const int beg = wslice * chunk;
    const int end = (beg + chunk < total) ? beg + chunk : total;
    const int lo = xcd * (Nn / NXCD);
    const int hi = lo + (Nn / NXCD);
    for (int idx = beg + threadIdx.x; idx < end; idx += 256) {
        int m = idx / Ee, e = idx - m * Ee;
        const int* eim = ei + (size_t)m * 2 * Ee;
        int d = eim[Ee + e];
        if (d >= lo && d < hi) {
            int s = eim[e];
            int pos = atomicAdd(cur + m * Nn + d, 1);
            esrc[(size_t)m * Ee + pos] = s;
        }
    }
}

// ============ weight prep ============
__global__ __launch_bounds__(256) void k_wcat(
    const float* __restrict__ W1l, const float* __restrict__ W1r,
    const float* __restrict__ W2l, const float* __restrict__ W2r,
    ushort* __restrict__ Wcat1, ushort* __restrict__ Wcat2)
{
    int idx = blockIdx.x * 256 + threadIdx.x;
    if (idx >= METAc * 384 * 128) return;
    int m = idx / (384 * 128);
    int rem = idx - m * 384 * 128;
    int j = rem >> 7;
    int k = rem & 127;
    if (j < 256) {
        float v = (j < 128) ? W1l[((size_t)m * 128 + k) * 128 + j]
                            : W1r[((size_t)m * 128 + k) * 128 + (j - 128)];
        Wcat1[((size_t)m * 256 + j) * 128 + k] = (ushort)f2bf(v);
    } else {
        int j2 = j - 256;
        float v = (j2 < 64) ? W2l[((size_t)m * 128 + k) * 64 + j2]
                            : W2r[((size_t)m * 128 + k) * 64 + (j2 - 64)];
        Wcat2[((size_t)m * 128 + j2) * 128 + k] = (ushort)f2bf(v);
    }
}

// ============ MFMA GEMM1: t1/r1 = x @ W1{l,r} (+b1 on z==1), bf16 out ============
__global__ __launch_bounds__(256) void k_mfma1(
    const float* __restrict__ x, const ushort* __restrict__ Wcat1,
    const float* __restrict__ b1, ushort* __restrict__ t1, ushort* __restrict__ r1)
{
    const int m = blockIdx.y, z = blockIdx.z;
    const int row0 = blockIdx.x * 128;
    const int tid = threadIdx.x;
    const int lane = tid & 63, w = tid >> 6;
    const int wr = w >> 1, wc = w & 1;

    __shared__ ushort As[128][136];   // 272B rows: 2-way bank aliasing only
    __shared__ ushort Bs[128][136];

    const float* Am = x + (size_t)m * Nn * 128;
    const ushort* Bm = Wcat1 + ((size_t)m * 256 + (size_t)z * 128) * 128;

    #pragma unroll
    for (int i = 0; i < 16; i++) {
        int f4 = tid + i * 256;
        int row = f4 >> 5, c4 = f4 & 31;
        int gr = row0 + row; if (gr >= Nn) gr = Nn - 1;
        float4 v = *(const float4*)(Am + (size_t)gr * 128 + c4 * 4);
        uint lo = f2bf(v.x) | (f2bf(v.y) << 16);
        uint hi = f2bf(v.z) | (f2bf(v.w) << 16);
        *(uint2*)&As[row][c4 * 4] = make_uint2(lo, hi);
    }
    #pragma unroll
    for (int i = 0; i < 8; i++) {
        int c8 = tid + i * 256;
        int row = c8 >> 4, c = c8 & 15;
        *(bf16x8*)&Bs[row][c * 8] = *(const bf16x8*)(Bm + (size_t)row * 128 + c * 8);
    }
    __syncthreads();

    f32x4 acc[4][4];
    #pragma unroll
    for (int i = 0; i < 4; i++)
        #pragma unroll
        for (int j = 0; j < 4; j++) acc[i][j] = (f32x4){0.f, 0.f, 0.f, 0.f};

    #pragma unroll
    for (int ks = 0; ks < 4; ks++) {
        bf16x8 a[4], b[4];
        #pragma unroll
        for (int i = 0; i < 4; i++)
            a[i] = *(const bf16x8*)&As[wr * 64 + i * 16 + (lane & 15)][ks * 32 + (lane >> 4) * 8];
        #pragma unroll
        for (int j = 0; j < 4; j++)
            b[j] = *(const bf16x8*)&Bs[wc * 64 + j * 16 + (lane & 15)][ks * 32 + (lane >> 4) * 8];
        #pragma unroll
        for (int i = 0; i < 4; i++)
            #pragma unroll
            for (int j = 0; j < 4; j++)
                acc[i][j] = mfma16(a[i], b[j], acc[i][j]);
    }

    ushort* outp = (z ? r1 : t1) + (size_t)m * Nn * 128;
    #pragma unroll
    for (int j = 0; j < 4; j++) {
        int col = wc * 64 + j * 16 + (lane & 15);
        float bias = z ? b1[m * 128 + col] : 0.0f;
        #pragma unroll
        for (int i = 0; i < 4; i++) {
            #pragma unroll
            for (int q = 0; q < 4; q++) {
                int row = row0 + wr * 64 + i * 16 + (lane >> 4) * 4 + q;
                if (row < Nn)
                    outp[(size_t)row * 128 + col] = (ushort)f2bf(acc[i][j][q] + bias);
            }
        }
    }
}

// ============ MFMA GEMM2 ============
__global__ __launch_bounds__(256) void k_mfma2(
    const ushort* __restrict__ h, const ushort* __restrict__ Wcat2,
    const float* __restrict__ b2, ushort* __restrict__ t2, ushort* __restrict__ r2)
{
    const int m = blockIdx.y;
    const int row0 = blockIdx.x * 128;
    const int tid = threadIdx.x;
    const int lane = tid & 63, w = tid >> 6;
    const int wr = w >> 1, wc = w & 1;

    __shared__ ushort As[128][136];
    __shared__ ushort Bs[128][136];

    const ushort* Am = h + (size_t)m * Nn * 128;
    const ushort* Bm = Wcat2 + (size_t)m * 128 * 128;

    #pragma unroll
    for (int i = 0; i < 8; i++) {
        int c8 = tid + i * 256;
        int row = c8 >> 4, c = c8 & 15;
        int gr = row0 + row; if (gr >= Nn) gr = Nn - 1;
        *(bf16x8*)&As[row][c * 8] = *(const bf16x8*)(Am + (size_t)gr * 128 + c * 8);
    }
    #pragma unroll
    for (int i = 0; i < 8; i++) {
        int c8 = tid + i * 256;
        int row = c8 >> 4, c = c8 & 15;
        *(bf16x8*)&Bs[row][c * 8] = *(const bf16x8*)(Bm + (size_t)row * 128 + c * 8);
    }
    __syncthreads();

    f32x4 acc[4][4];
    #pragma unroll
    for (int i = 0; i < 4; i++)
        #pragma unroll
        for (int j = 0; j < 4; j++) acc[i][j] = (f32x4){0.f, 0.f, 0.f, 0.f};

    #pragma unroll
    for (int ks = 0; ks < 4; ks++) {
        bf16x8 a[4], b[4];
        #pragma unroll
        for (int i = 0; i < 4; i++)
            a[i] = *(const bf16x8*)&As[wr * 64 + i * 16 + (lane & 15)][ks * 32 + (lane >> 4) * 8];
        #pragma unroll
        for (int j = 0; j < 4; j++)
            b[j] = *(const bf16x8*)&Bs[wc * 64 + j * 16 + (lane & 15)][ks * 32 + (lane >> 4) * 8];
        #pragma unroll
        for (int i = 0; i < 4; i++)
            #pragma unroll
            for (int j = 0; j < 4; j++)
                acc[i][j] = mfma16(a[i], b[j], acc[i][j]);
    }

    ushort* outp = (wc ? r2 : t2) + (size_t)m * Nn * 64;
    #pragma unroll
    for (int j = 0; j < 4; j++) {
        int cl = j * 16 + (lane & 15);
        float bias = wc ? b2[m * 64 + cl] : 0.0f;
        #pragma unroll
        for (int i = 0; i < 4; i++) {
            #pragma unroll
            for (int q = 0; q < 4; q++) {
                int row = row0 + wr * 64 + i * 16 + (lane >> 4) * 4 + q;
                if (row < Nn)
                    outp[(size_t)row * 64 + cl] = (ushort)f2bf(acc[i][j][q] + bias);
            }
        }
    }
}

// ============ agg1: h = ELU(mean-gather(t1) + r1), bf16. MLP-deep version ============
// One node per wave. 4 lane-groups x uint4 (16B) cover a 256B row -> 4 edges
// per issue, x2 software pipeline -> 8 gathers in flight. Loads use clamped
// indices (always issued); only the accumulate is predicated.
__global__ __launch_bounds__(256) void k_agg_elu(
    const ushort* __restrict__ t1, const ushort* __restrict__ r1,
    const int* __restrict__ off, const int* __restrict__ cnt,
    const float* __restrict__ inv, const int* __restrict__ esrc,
    ushort* __restrict__ h)
{
    int gwid = (blockIdx.x * 256 + threadIdx.x) >> 6;
    if (gwid >= METAc * Nn) return;
    int m = gwid / Nn, n = gwid - m * Nn;
    int lane = threadIdx.x & 63;
    int g = lane >> 4;        // 0..3: edge slot
    int sub = lane & 15;      // 16 lanes x 16B = 256B row
    int start = off[m * Nn + n];
    int c = cnt[m * Nn + n];
    const int* es = esrc + (size_t)m * Ee;
    const ushort* tm = t1 + (size_t)m * Nn * 128;

    float a[8];
    #pragma unroll
    for (int k = 0; k < 8; k++) a[k] = 0.0f;

    for (int e = 0; e < c; e += 8) {
        int e0 = e + g, e1 = e + 4 + g;
        bool p0 = e0 < c, p1 = e1 < c;
        int i0 = p0 ? e0 : c - 1;
        int i1 = p1 ? e1 : c - 1;
        int s0 = es[start + i0];
        int s1 = es[start + i1];
        uint4 v0 = *(const uint4*)(tm + (size_t)s0 * 128 + sub * 8);
        uint4 v1 = *(const uint4*)(tm + (size_t)s1 * 128 + sub * 8);
        if (p0) {
            a[0] += bf2f(v0.x & 0xffffu); a[1] += bf2f(v0.x >> 16);
            a[2] += bf2f(v0.y & 0xffffu); a[3] += bf2f(v0.y >> 16);
            a[4] += bf2f(v0.z & 0xffffu); a[5] += bf2f(v0.z >> 16);
            a[6] += bf2f(v0.w & 0xffffu); a[7] += bf2f(v0.w >> 16);
        }
        if (p1) {
            a[0] += bf2f(v1.x & 0xffffu); a[1] += bf2f(v1.x >> 16);
            a[2] += bf2f(v1.y & 0xffffu); a[3] += bf2f(v1.y >> 16);
            a[4] += bf2f(v1.z & 0xffffu); a[5] += bf2f(v1.z >> 16);
            a[6] += bf2f(v1.w & 0xffffu); a[7] += bf2f(v1.w >> 16);
        }
    }
    // reduce the 4 edge-slots (lane bits 4,5)
    #pragma unroll
    for (int k = 0; k < 8; k++) {
        a[k] += __shfl_xor(a[k], 16);
        a[k] += __shfl_xor(a[k], 32);
    }

    float iv = inv[m * Nn + n];
    uint4 rv = *(const uint4*)(r1 + ((size_t)m * Nn + n) * 128 + sub * 8);
    uint rr[4] = {rv.x, rv.y, rv.z, rv.w};
    uint o[4];
    #pragma unroll
    for (int k = 0; k < 4; k++) {
        float z0 = a[2 * k] * iv + bf2f(rr[k] & 0xffffu);
        float z1 = a[2 * k + 1] * iv + bf2f(rr[k] >> 16);
        z0 = z0 > 0.0f ? z0 : expm1f(z0);
        z1 = z1 > 0.0f ? z1 : expm1f(z1);
        o[k] = f2bf(z0) | (f2bf(z1) << 16);
    }
    if (g == 0) {
        *(uint4*)(h + ((size_t)m * Nn + n) * 128 + sub * 8) = make_uint4(o[0], o[1], o[2], o[3]);
    }
}

// ============ agg2: out = log_softmax(mean-gather(t2) + r2). MLP-deep version ============
// 8 lane-groups x uint4 (16B) cover the 128B row -> 8 edges in flight per issue.
__global__ __launch_bounds__(256) void k_agg_lsm(
    const ushort* __restrict__ t2, const ushort* __restrict__ r2,
    const int* __restrict__ off, const int* __restrict__ cnt,
    const float* __restrict__ inv, const int* __restrict__ esrc,
    float* __restrict__ out)
{
    int gwid = (blockIdx.x * 256 + threadIdx.x) >> 6;
    if (gwid >= METAc * Nn) return;
    int m = gwid / Nn, n = gwid - m * Nn;
    int lane = threadIdx.x & 63;
    int g = lane >> 3;        // 0..7: edge slot
    int sub = lane & 7;       // 8 lanes x 16B = 128B row
    int start = off[m * Nn + n];
    int c = cnt[m * Nn + n];
    const int* es = esrc + (size_t)m * Ee;
    const ushort* tm = t2 + (size_t)m * Nn * 64;

    float a[8];
    #pragma unroll
    for (int k = 0; k < 8; k++) a[k] = 0.0f;

    for (int e = 0; e < c; e += 8) {
        int e0 = e + g;
        bool p0 = e0 < c;
        int i0 = p0 ? e0 : c - 1;
        int s0 = es[start + i0];
        uint4 v0 = *(const uint4*)(tm + (size_t)s0 * 64 + sub * 8);
        if (p0) {
            a[0] += bf2f(v0.x & 0xffffu); a[1] += bf2f(v0.x >> 16);
            a[2] += bf2f(v0.y & 0xffffu); a[3] += bf2f(v0.y >> 16);
            a[4] += bf2f(v0.z & 0xffffu); a[5] += bf2f(v0.z >> 16);
            a[6] += bf2f(v0.w & 0xffffu); a[7] += bf2f(v0.w >> 16);
        }
    }
    // reduce the 8 edge-slots (lane bits 3,4,5)
    #pragma unroll
    for (int k = 0; k < 8; k++) {
        a[k] += __shfl_xor(a[k], 8);
        a[k] += __shfl_xor(a[k], 16);
        a[k] += __shfl_xor(a[k], 32);
    }

    float iv = inv[m * Nn + n];
    uint4 rv = *(const uint4*)(r2 + ((size_t)m * Nn + n) * 64 + sub * 8);
    uint rr[4] = {rv.x, rv.y, rv.z, rv.w};
    float z[8];
    #pragma unroll
    for (int k = 0; k < 4; k++) {
        z[2 * k]     = a[2 * k] * iv + bf2f(rr[k] & 0xffffu);
        z[2 * k + 1] = a[2 * k + 1] * iv + bf2f(rr[k] >> 16);
    }
    float mx = z[0];
    #pragma unroll
    for (int k = 1; k < 8; k++) mx = fmaxf(mx, z[k]);
    #pragma unroll
    for (int o = 1; o <= 4; o <<= 1) mx = fmaxf(mx, __shfl_xor(mx, o));
    float s = 0.0f;
    #pragma unroll
    for (int k = 0; k < 8; k++) s += expf(z[k] - mx);
    #pragma unroll
    for (int o = 1; o <= 4; o <<= 1) s += __shfl_xor(s, o);
    float lse = mx + logf(s);
    if (g == 0) {
        float* op = out + ((size_t)m * Nn + n) * 64 + sub * 8;
        *(float4*)op       = make_float4(z[0] - lse, z[1] - lse, z[2] - lse, z[3] - lse);
        *(float4*)(op + 4) = make_float4(z[4] - lse, z[5] - lse, z[6] - lse, z[7] - lse);
    }
}

extern "C" void kernel_launch(void* const* d_in, const int* in_sizes, int n_in,
                              void* d_out, int out_size, void* d_ws, size_t ws_size,
                              hipStream_t stream) {
    const float* meta_x = (const float*)d_in[0];
    const int*   ei     = (const int*)d_in[1];
    const float* W1l    = (const float*)d_in[2];
    const float* W1r    = (const float*)d_in[3];
    const float* b1     = (const float*)d_in[4];
    const float* W2l    = (const float*)d_in[5];
    const float* W2r    = (const float*)d_in[6];
    const float* b2     = (const float*)d_in[7];
    float* out = (float*)d_out;

    const size_t nN = (size_t)METAc * Nn;

    float* inv  = (float*)d_ws;
    int*   cnt  = (int*)(inv + nN);
    int*   off  = cnt + nN;
    int*   cur  = off + nN;
    int*   csum = cur + nN;
    int*   esrc = csum + 64 * METAc;
    ushort* t1  = (ushort*)(esrc + (size_t)METAc * Ee);
    ushort* r1  = t1 + nN * 128;
    ushort* h   = r1 + nN * 128;
    ushort* t2  = h + nN * 128;
    ushort* r2  = t2 + nN * 64;
    ushort* Wcat1 = r2 + nN * 64;                       // META*256*128
    ushort* Wcat2 = Wcat1 + (size_t)METAc * 256 * 128;  // META*128*128

    hipMemsetAsync(cnt, 0, nN * sizeof(int), stream);
    k_count<<<(METAc * Ee + 255) / 256, 256, 0, stream>>>(ei, cnt);
    k_chunksum<<<METAc * NCH, 1024, 0, stream>>>(cnt, csum);
    k_chunkscan<<<1, 256, 0, stream>>>(csum);
    k_scan<<<METAc * NCH, 1024, 0, stream>>>(cnt, csum, off, cur, inv);
    k_fill2<<<NXCD * FILL_WPX, 256, 0, stream>>>(ei, cur, esrc);
    k_wcat<<<(METAc * 384 * 128 + 255) / 256, 256, 0, stream>>>(W1l, W1r, W2l, W2r, Wcat1, Wcat2);

    k_mfma1<<<dim3((Nn + 127) / 128, METAc, 2), 256, 0, stream>>>(meta_x, Wcat1, b1, t1, r1);
    k_agg_elu<<<(METAc * Nn * 64 + 255) / 256, 256, 0, stream>>>(t1, r1, off, cnt, inv, esrc, h);
    k_mfma2<<<dim3((Nn + 127) / 128, METAc, 1), 256, 0, stream>>>(h, Wcat2, b2, t2, r2);
    k_agg_lsm<<<(METAc * Nn * 64 + 255) / 256, 256, 0, stream>>>(t2, r2, off, cnt, inv, esrc, out);
}

// Round 7
// 465.327 us; speedup vs baseline: 14.5541x; 1.0335x over previous
//
#include <hip/hip_runtime.h>

#define METAc 3
#define Nn 50000
#define Ee 640000
#define CHUNK 1024
#define NCH 49   // ceil(Nn/CHUNK)
#define NXCD 8
#define FILL_WPX 128   // workgroups per XCD-slice for k_fill2

typedef unsigned int uint;
typedef unsigned short ushort;
typedef __attribute__((ext_vector_type(8))) short bf16x8;
typedef __attribute__((ext_vector_type(4))) float f32x4;
typedef __attribute__((ext_vector_type(2))) float f32x2;

__device__ __forceinline__ float bf2f(uint u16) {
    union { uint u; float f; } v; v.u = u16 << 16; return v.f;
}
__device__ __forceinline__ uint f2bf(float f) {
    union { float f; uint u; } v; v.f = f;
    return (v.u + 0x7fffu + ((v.u >> 16) & 1u)) >> 16;
}
// unpack 2 packed bf16 -> float2 {lo, hi} in 2 VALU ops; add is 1 v_pk_add_f32
__device__ __forceinline__ f32x2 up2(uint u) {
    union { uint2 u2; f32x2 f; } cv;
    cv.u2.x = u << 16;
    cv.u2.y = u & 0xffff0000u;
    return cv.f;
}
__device__ __forceinline__ f32x4 mfma16(bf16x8 a, bf16x8 b, f32x4 c) {
    return __builtin_amdgcn_mfma_f32_16x16x32_bf16(a, b, c, 0, 0, 0);
}

// ================= CSR build =================
__global__ __launch_bounds__(256) void k_count(const int* __restrict__ ei, int* __restrict__ cnt) {
    int idx = blockIdx.x * 256 + threadIdx.x;
    if (idx >= METAc * Ee) return;
    int m = idx / Ee, e = idx - m * Ee;
    int dst = ei[(size_t)m * 2 * Ee + Ee + e];
    atomicAdd(cnt + m * Nn + dst, 1);
}

__global__ __launch_bounds__(1024) void k_chunksum(const int* __restrict__ cnt, int* __restrict__ csum) {
    int m = blockIdx.x / NCH, ch = blockIdx.x - m * NCH;
    int tid = threadIdx.x;
    int i = ch * CHUNK + tid;
    int v = (i < Nn) ? cnt[m * Nn + i] : 0;
    #pragma unroll
    for (int o = 1; o < 64; o <<= 1) v += __shfl_xor(v, o);
    __shared__ int ws_[16];
    int lane = tid & 63, w = tid >> 6;
    if (lane == 0) ws_[w] = v;
    __syncthreads();
    if (tid == 0) {
        int s = 0;
        #pragma unroll
        for (int k = 0; k < 16; k++) s += ws_[k];
        csum[m * 64 + ch] = s;
    }
}

__global__ __launch_bounds__(256) void k_chunkscan(int* __restrict__ csum) {
    int tid = threadIdx.x;
    int w = tid >> 6, lane = tid & 63;
    if (w >= METAc) return;
    int v = (lane < NCH) ? csum[w * 64 + lane] : 0;
    int orig = v;
    #pragma unroll
    for (int o = 1; o < 64; o <<= 1) { int t = __shfl_up(v, o); if (lane >= o) v += t; }
    if (lane < NCH) csum[w * 64 + lane] = v - orig;
}

__global__ __launch_bounds__(1024) void k_scan(const int* __restrict__ cnt, const int* __restrict__ csum,
                                               int* __restrict__ off, int* __restrict__ cur,
                                               float* __restrict__ inv) {
    int m = blockIdx.x / NCH, ch = blockIdx.x - m * NCH;
    int tid = threadIdx.x;
    int i = ch * CHUNK + tid;
    int c = (i < Nn) ? cnt[m * Nn + i] : 0;
    int lane = tid & 63, w = tid >> 6;
    int v = c;
    #pragma unroll
    for (int o = 1; o < 64; o <<= 1) { int t = __shfl_up(v, o); if (lane >= o) v += t; }
    __shared__ int ws_[16];
    if (lane == 63) ws_[w] = v;
    __syncthreads();
    if (tid < 16) {
        int s = ws_[tid];
        #pragma unroll
        for (int o = 1; o < 16; o <<= 1) { int t = __shfl_up(s, o); if (lane >= o) s += t; }
        ws_[tid] = s;
    }
    __syncthreads();
    int base = (w > 0) ? ws_[w - 1] : 0;
    if (i < Nn) {
        int g = csum[m * 64 + ch] + base + v - c;
        off[m * Nn + i] = g;
        cur[m * Nn + i] = g;
        inv[m * Nn + i] = 1.0f / fmaxf((float)c, 1.0f);
    }
}

// XCD-local CSR fill: workgroup b owns dst range [(b%8)*6250, (b%8+1)*6250).
__global__ __launch_bounds__(256) void k_fill2(const int* __restrict__ ei, int* __restrict__ cur,
                                               int* __restrict__ esrc) {
    const int xcd = blockIdx.x & (NXCD - 1);
    const int wslice = blockIdx.x >> 3;
    const int total = METAc * Ee;
    const int chunk = (total + FILL_WPX - 1) / FILL_WPX;
    const int beg = wslice * chunk;
    const int end = (beg + chunk < total) ? beg + chunk : total;
    const int lo = xcd * (Nn / NXCD);
    const int hi = lo + (Nn / NXCD);
    for (int idx = beg + threadIdx.x; idx < end; idx += 256) {
        int m = idx / Ee, e = idx - m * Ee;
        const int* eim = ei + (size_t)m * 2 * Ee;
        int d = eim[Ee + e];
        if (d >= lo && d < hi) {
            int s = eim[e];
            int pos = atomicAdd(cur + m * Nn + d, 1);
            esrc[(size_t)m * Ee + pos] = s;
        }
    }
}

// ============ weight prep ============
__global__ __launch_bounds__(256) void k_wcat(
    const float* __restrict__ W1l, const float* __restrict__ W1r,
    const float* __restrict__ W2l, const float* __restrict__ W2r,
    ushort* __restrict__ Wcat1, ushort* __restrict__ Wcat2)
{
    int idx = blockIdx.x * 256 + threadIdx.x;
    if (idx >= METAc * 384 * 128) return;
    int m = idx / (384 * 128);
    int rem = idx - m * 384 * 128;
    int j = rem >> 7;
    int k = rem & 127;
    if (j < 256) {
        float v = (j < 128) ? W1l[((size_t)m * 128 + k) * 128 + j]
                            : W1r[((size_t)m * 128 + k) * 128 + (j - 128)];
        Wcat1[((size_t)m * 256 + j) * 128 + k] = (ushort)f2bf(v);
    } else {
        int j2 = j - 256;
        float v = (j2 < 64) ? W2l[((size_t)m * 128 + k) * 64 + j2]
                            : W2r[((size_t)m * 128 + k) * 64 + (j2 - 64)];
        Wcat2[((size_t)m * 128 + j2) * 128 + k] = (ushort)f2bf(v);
    }
}

// ============ MFMA GEMM1: t1/r1 = x @ W1{l,r} (+b1 on z==1), bf16 out ============
__global__ __launch_bounds__(256) void k_mfma1(
    const float* __restrict__ x, const ushort* __restrict__ Wcat1,
    const float* __restrict__ b1, ushort* __restrict__ t1, ushort* __restrict__ r1)
{
    const int m = blockIdx.y, z = blockIdx.z;
    const int row0 = blockIdx.x * 128;
    const int tid = threadIdx.x;
    const int lane = tid & 63, w = tid >> 6;
    const int wr = w >> 1, wc = w & 1;

    __shared__ ushort As[128][136];   // 272B rows: 2-way bank aliasing only
    __shared__ ushort Bs[128][136];

    const float* Am = x + (size_t)m * Nn * 128;
    const ushort* Bm = Wcat1 + ((size_t)m * 256 + (size_t)z * 128) * 128;

    #pragma unroll
    for (int i = 0; i < 16; i++) {
        int f4 = tid + i * 256;
        int row = f4 >> 5, c4 = f4 & 31;
        int gr = row0 + row; if (gr >= Nn) gr = Nn - 1;
        float4 v = *(const float4*)(Am + (size_t)gr * 128 + c4 * 4);
        uint lo = f2bf(v.x) | (f2bf(v.y) << 16);
        uint hi = f2bf(v.z) | (f2bf(v.w) << 16);
        *(uint2*)&As[row][c4 * 4] = make_uint2(lo, hi);
    }
    #pragma unroll
    for (int i = 0; i < 8; i++) {
        int c8 = tid + i * 256;
        int row = c8 >> 4, c = c8 & 15;
        *(bf16x8*)&Bs[row][c * 8] = *(const bf16x8*)(Bm + (size_t)row * 128 + c * 8);
    }
    __syncthreads();

    f32x4 acc[4][4];
    #pragma unroll
    for (int i = 0; i < 4; i++)
        #pragma unroll
        for (int j = 0; j < 4; j++) acc[i][j] = (f32x4){0.f, 0.f, 0.f, 0.f};

    #pragma unroll
    for (int ks = 0; ks < 4; ks++) {
        bf16x8 a[4], b[4];
        #pragma unroll
        for (int i = 0; i < 4; i++)
            a[i] = *(const bf16x8*)&As[wr * 64 + i * 16 + (lane & 15)][ks * 32 + (lane >> 4) * 8];
        #pragma unroll
        for (int j = 0; j < 4; j++)
            b[j] = *(const bf16x8*)&Bs[wc * 64 + j * 16 + (lane & 15)][ks * 32 + (lane >> 4) * 8];
        #pragma unroll
        for (int i = 0; i < 4; i++)
            #pragma unroll
            for (int j = 0; j < 4; j++)
                acc[i][j] = mfma16(a[i], b[j], acc[i][j]);
    }

    ushort* outp = (z ? r1 : t1) + (size_t)m * Nn * 128;
    #pragma unroll
    for (int j = 0; j < 4; j++) {
        int col = wc * 64 + j * 16 + (lane & 15);
        float bias = z ? b1[m * 128 + col] : 0.0f;
        #pragma unroll
        for (int i = 0; i < 4; i++) {
            #pragma unroll
            for (int q = 0; q < 4; q++) {
                int row = row0 + wr * 64 + i * 16 + (lane >> 4) * 4 + q;
                if (row < Nn)
                    outp[(size_t)row * 128 + col] = (ushort)f2bf(acc[i][j][q] + bias);
            }
        }
    }
}

// ============ MFMA GEMM2 ============
__global__ __launch_bounds__(256) void k_mfma2(
    const ushort* __restrict__ h, const ushort* __restrict__ Wcat2,
    const float* __restrict__ b2, ushort* __restrict__ t2, ushort* __restrict__ r2)
{
    const int m = blockIdx.y;
    const int row0 = blockIdx.x * 128;
    const int tid = threadIdx.x;
    const int lane = tid & 63, w = tid >> 6;
    const int wr = w >> 1, wc = w & 1;

    __shared__ ushort As[128][136];
    __shared__ ushort Bs[128][136];

    const ushort* Am = h + (size_t)m * Nn * 128;
    const ushort* Bm = Wcat2 + (size_t)m * 128 * 128;

    #pragma unroll
    for (int i = 0; i < 8; i++) {
        int c8 = tid + i * 256;
        int row = c8 >> 4, c = c8 & 15;
        int gr = row0 + row; if (gr >= Nn) gr = Nn - 1;
        *(bf16x8*)&As[row][c * 8] = *(const bf16x8*)(Am + (size_t)gr * 128 + c * 8);
    }
    #pragma unroll
    for (int i = 0; i < 8; i++) {
        int c8 = tid + i * 256;
        int row = c8 >> 4, c = c8 & 15;
        *(bf16x8*)&Bs[row][c * 8] = *(const bf16x8*)(Bm + (size_t)row * 128 + c * 8);
    }
    __syncthreads();

    f32x4 acc[4][4];
    #pragma unroll
    for (int i = 0; i < 4; i++)
        #pragma unroll
        for (int j = 0; j < 4; j++) acc[i][j] = (f32x4){0.f, 0.f, 0.f, 0.f};

    #pragma unroll
    for (int ks = 0; ks < 4; ks++) {
        bf16x8 a[4], b[4];
        #pragma unroll
        for (int i = 0; i < 4; i++)
            a[i] = *(const bf16x8*)&As[wr * 64 + i * 16 + (lane & 15)][ks * 32 + (lane >> 4) * 8];
        #pragma unroll
        for (int j = 0; j < 4; j++)
            b[j] = *(const bf16x8*)&Bs[wc * 64 + j * 16 + (lane & 15)][ks * 32 + (lane >> 4) * 8];
        #pragma unroll
        for (int i = 0; i < 4; i++)
            #pragma unroll
            for (int j = 0; j < 4; j++)
                acc[i][j] = mfma16(a[i], b[j], acc[i][j]);
    }

    ushort* outp = (wc ? r2 : t2) + (size_t)m * Nn * 64;
    #pragma unroll
    for (int j = 0; j < 4; j++) {
        int cl = j * 16 + (lane & 15);
        float bias = wc ? b2[m * 64 + cl] : 0.0f;
        #pragma unroll
        for (int i = 0; i < 4; i++) {
            #pragma unroll
            for (int q = 0; q < 4; q++) {
                int row = row0 + wr * 64 + i * 16 + (lane >> 4) * 4 + q;
                if (row < Nn)
                    outp[(size_t)row * 64 + cl] = (ushort)f2bf(acc[i][j][q] + bias);
            }
        }
    }
}

// ============ agg1: h = ELU(mean-gather(t1) + r1), bf16 ============
// One node per wave; 4 edge-slots x 16 lanes x 16B. Main loop: 16 edges/iter,
// 4 uint4 loads in flight, NO predicates (full groups only). Packed f32x2
// accumulate (v_pk_add_f32): 3 VALU per 2 elements. Divergent tail loop.
__global__ __launch_bounds__(256) void k_agg_elu(
    const ushort* __restrict__ t1, const ushort* __restrict__ r1,
    const int* __restrict__ off, const int* __restrict__ cnt,
    const float* __restrict__ inv, const int* __restrict__ esrc,
    ushort* __restrict__ h)
{
    int gwid = (blockIdx.x * 256 + threadIdx.x) >> 6;
    if (gwid >= METAc * Nn) return;
    int m = gwid / Nn, n = gwid - m * Nn;
    int lane = threadIdx.x & 63;
    int g = lane >> 4;        // 0..3: edge slot
    int sub = lane & 15;      // 16 lanes x 16B = 256B row
    int start = off[m * Nn + n];
    int c = cnt[m * Nn + n];
    const int* es = esrc + (size_t)m * Ee + start;
    const ushort* tm = t1 + (size_t)m * Nn * 128;

    f32x2 a[4];
    #pragma unroll
    for (int k = 0; k < 4; k++) a[k] = (f32x2){0.f, 0.f};

    int nfull = c & ~15;
    for (int e = 0; e < nfull; e += 16) {
        int s0 = es[e + g];
        int s1 = es[e + 4 + g];
        int s2 = es[e + 8 + g];
        int s3 = es[e + 12 + g];
        uint4 v0 = *(const uint4*)(tm + (size_t)s0 * 128 + sub * 8);
        uint4 v1 = *(const uint4*)(tm + (size_t)s1 * 128 + sub * 8);
        uint4 v2 = *(const uint4*)(tm + (size_t)s2 * 128 + sub * 8);
        uint4 v3 = *(const uint4*)(tm + (size_t)s3 * 128 + sub * 8);
        a[0] += up2(v0.x); a[1] += up2(v0.y); a[2] += up2(v0.z); a[3] += up2(v0.w);
        a[0] += up2(v1.x); a[1] += up2(v1.y); a[2] += up2(v1.z); a[3] += up2(v1.w);
        a[0] += up2(v2.x); a[1] += up2(v2.y); a[2] += up2(v2.z); a[3] += up2(v2.w);
        a[0] += up2(v3.x); a[1] += up2(v3.y); a[2] += up2(v3.z); a[3] += up2(v3.w);
    }
    for (int e = nfull + g; e < c; e += 4) {   // divergent tail, no clamps
        int s0 = es[e];
        uint4 v0 = *(const uint4*)(tm + (size_t)s0 * 128 + sub * 8);
        a[0] += up2(v0.x); a[1] += up2(v0.y); a[2] += up2(v0.z); a[3] += up2(v0.w);
    }
    // reduce the 4 edge-slots (lane bits 4,5)
    #pragma unroll
    for (int k = 0; k < 4; k++) {
        a[k].x += __shfl_xor(a[k].x, 16);  a[k].y += __shfl_xor(a[k].y, 16);
        a[k].x += __shfl_xor(a[k].x, 32);  a[k].y += __shfl_xor(a[k].y, 32);
    }

    float iv = inv[m * Nn + n];
    uint4 rv = *(const uint4*)(r1 + ((size_t)m * Nn + n) * 128 + sub * 8);
    uint rr[4] = {rv.x, rv.y, rv.z, rv.w};
    uint o[4];
    #pragma unroll
    for (int k = 0; k < 4; k++) {
        float z0 = a[k].x * iv + bf2f(rr[k] & 0xffffu);
        float z1 = a[k].y * iv + bf2f(rr[k] >> 16);
        z0 = z0 > 0.0f ? z0 : expm1f(z0);
        z1 = z1 > 0.0f ? z1 : expm1f(z1);
        o[k] = f2bf(z0) | (f2bf(z1) << 16);
    }
    if (g == 0) {
        *(uint4*)(h + ((size_t)m * Nn + n) * 128 + sub * 8) = make_uint4(o[0], o[1], o[2], o[3]);
    }
}

// ============ agg2: out = log_softmax(mean-gather(t2) + r2) ============
// 8 edge-slots x 8 lanes x 16B. Main loop: 16 edges/iter, no predicates,
// packed accumulate. Divergent tail.
__global__ __launch_bounds__(256) void k_agg_lsm(
    const ushort* __restrict__ t2, const ushort* __restrict__ r2,
    const int* __restrict__ off, const int* __restrict__ cnt,
    const float* __restrict__ inv, const int* __restrict__ esrc,
    float* __restrict__ out)
{
    int gwid = (blockIdx.x * 256 + threadIdx.x) >> 6;
    if (gwid >= METAc * Nn) return;
    int m = gwid / Nn, n = gwid - m * Nn;
    int lane = threadIdx.x & 63;
    int g = lane >> 3;        // 0..7: edge slot
    int sub = lane & 7;       // 8 lanes x 16B = 128B row
    int start = off[m * Nn + n];
    int c = cnt[m * Nn + n];
    const int* es = esrc + (size_t)m * Ee + start;
    const ushort* tm = t2 + (size_t)m * Nn * 64;

    f32x2 a[4];
    #pragma unroll
    for (int k = 0; k < 4; k++) a[k] = (f32x2){0.f, 0.f};

    int nfull = c & ~15;
    for (int e = 0; e < nfull; e += 16) {
        int s0 = es[e + g];
        int s1 = es[e + 8 + g];
        uint4 v0 = *(const uint4*)(tm + (size_t)s0 * 64 + sub * 8);
        uint4 v1 = *(const uint4*)(tm + (size_t)s1 * 64 + sub * 8);
        a[0] += up2(v0.x); a[1] += up2(v0.y); a[2] += up2(v0.z); a[3] += up2(v0.w);
        a[0] += up2(v1.x); a[1] += up2(v1.y); a[2] += up2(v1.z); a[3] += up2(v1.w);
    }
    for (int e = nfull + g; e < c; e += 8) {   // divergent tail
        int s0 = es[e];
        uint4 v0 = *(const uint4*)(tm + (size_t)s0 * 64 + sub * 8);
        a[0] += up2(v0.x); a[1] += up2(v0.y); a[2] += up2(v0.z); a[3] += up2(v0.w);
    }
    // reduce the 8 edge-slots (lane bits 3,4,5)
    #pragma unroll
    for (int k = 0; k < 4; k++) {
        a[k].x += __shfl_xor(a[k].x, 8);   a[k].y += __shfl_xor(a[k].y, 8);
        a[k].x += __shfl_xor(a[k].x, 16);  a[k].y += __shfl_xor(a[k].y, 16);
        a[k].x += __shfl_xor(a[k].x, 32);  a[k].y += __shfl_xor(a[k].y, 32);
    }

    float iv = inv[m * Nn + n];
    uint4 rv = *(const uint4*)(r2 + ((size_t)m * Nn + n) * 64 + sub * 8);
    uint rr[4] = {rv.x, rv.y, rv.z, rv.w};
    float z[8];
    #pragma unroll
    for (int k = 0; k < 4; k++) {
        z[2 * k]     = a[k].x * iv + bf2f(rr[k] & 0xffffu);
        z[2 * k + 1] = a[k].y * iv + bf2f(rr[k] >> 16);
    }
    float mx = z[0];
    #pragma unroll
    for (int k = 1; k < 8; k++) mx = fmaxf(mx, z[k]);
    #pragma unroll
    for (int o = 1; o <= 4; o <<= 1) mx = fmaxf(mx, __shfl_xor(mx, o));
    float s = 0.0f;
    #pragma unroll
    for (int k = 0; k < 8; k++) s += expf(z[k] - mx);
    #pragma unroll
    for (int o = 1; o <= 4; o <<= 1) s += __shfl_xor(s, o);
    float lse = mx + logf(s);
    if (g == 0) {
        float* op = out + ((size_t)m * Nn + n) * 64 + sub * 8;
        *(float4*)op       = make_float4(z[0] - lse, z[1] - lse, z[2] - lse, z[3] - lse);
        *(float4*)(op + 4) = make_float4(z[4] - lse, z[5] - lse, z[6] - lse, z[7] - lse);
    }
}

extern "C" void kernel_launch(void* const* d_in, const int* in_sizes, int n_in,
                              void* d_out, int out_size, void* d_ws, size_t ws_size,
                              hipStream_t stream) {
    const float* meta_x = (const float*)d_in[0];
    const int*   ei     = (const int*)d_in[1];
    const float* W1l    = (const float*)d_in[2];
    const float* W1r    = (const float*)d_in[3];
    const float* b1     = (const float*)d_in[4];
    const float* W2l    = (const float*)d_in[5];
    const float* W2r    = (const float*)d_in[6];
    const float* b2     = (const float*)d_in[7];
    float* out = (float*)d_out;

    const size_t nN = (size_t)METAc * Nn;

    float* inv  = (float*)d_ws;
    int*   cnt  = (int*)(inv + nN);
    int*   off  = cnt + nN;
    int*   cur  = off + nN;
    int*   csum = cur + nN;
    int*   esrc = csum + 64 * METAc;
    ushort* t1  = (ushort*)(esrc + (size_t)METAc * Ee);
    ushort* r1  = t1 + nN * 128;
    ushort* h   = r1 + nN * 128;
    ushort* t2  = h + nN * 128;
    ushort* r2  = t2 + nN * 64;
    ushort* Wcat1 = r2 + nN * 64;                       // META*256*128
    ushort* Wcat2 = Wcat1 + (size_t)METAc * 256 * 128;  // META*128*128

    hipMemsetAsync(cnt, 0, nN * sizeof(int), stream);
    k_count<<<(METAc * Ee + 255) / 256, 256, 0, stream>>>(ei, cnt);
    k_chunksum<<<METAc * NCH, 1024, 0, stream>>>(cnt, csum);
    k_chunkscan<<<1, 256, 0, stream>>>(csum);
    k_scan<<<METAc * NCH, 1024, 0, stream>>>(cnt, csum, off, cur, inv);
    k_fill2<<<NXCD * FILL_WPX, 256, 0, stream>>>(ei, cur, esrc);
    k_wcat<<<(METAc * 384 * 128 + 255) / 256, 256, 0, stream>>>(W1l, W1r, W2l, W2r, Wcat1, Wcat2);

    k_mfma1<<<dim3((Nn + 127) / 128, METAc, 2), 256, 0, stream>>>(meta_x, Wcat1, b1, t1, r1);
    k_agg_elu<<<(METAc * Nn * 64 + 255) / 256, 256, 0, stream>>>(t1, r1, off, cnt, inv, esrc, h);
    k_mfma2<<<dim3((Nn + 127) / 128, METAc, 1), 256, 0, stream>>>(h, Wcat2, b2, t2, r2);
    k_agg_lsm<<<(METAc * Nn * 64 + 255) / 256, 256, 0, stream>>>(t2, r2, off, cnt, inv, esrc, out);
}

// Round 9
// 455.750 us; speedup vs baseline: 14.8599x; 1.0210x over previous
//
#include <hip/hip_runtime.h>

#define METAc 3
#define Nn 50000
#define Ee 640000
#define CHUNK 1024
#define NCH 49   // ceil(Nn/CHUNK)
#define NXCD 8
#define FILL_WPX 256   // workgroups per XCD-slice for k_fill2

typedef unsigned int uint;
typedef unsigned short ushort;
typedef __attribute__((ext_vector_type(8))) short bf16x8;
typedef __attribute__((ext_vector_type(4))) float f32x4;
typedef __attribute__((ext_vector_type(2))) float f32x2;
typedef __attribute__((ext_vector_type(4))) uint uint4v;   // native vector: OK for nontemporal builtins

__device__ __forceinline__ float bf2f(uint u16) {
    union { uint u; float f; } v; v.u = u16 << 16; return v.f;
}
__device__ __forceinline__ uint f2bf(float f) {
    union { float f; uint u; } v; v.f = f;
    return (v.u + 0x7fffu + ((v.u >> 16) & 1u)) >> 16;
}
// unpack 2 packed bf16 -> float2 {lo, hi}; add is 1 v_pk_add_f32
__device__ __forceinline__ f32x2 up2(uint u) {
    union { uint2 u2; f32x2 f; } cv;
    cv.u2.x = u << 16;
    cv.u2.y = u & 0xffff0000u;
    return cv.f;
}
__device__ __forceinline__ f32x4 mfma16(bf16x8 a, bf16x8 b, f32x4 c) {
    return __builtin_amdgcn_mfma_f32_16x16x32_bf16(a, b, c, 0, 0, 0);
}
__device__ __forceinline__ uint4v nt_load4(const void* p) {
    return __builtin_nontemporal_load((const uint4v*)p);
}

// ================= CSR build =================
// count: 4 edges/thread via nontemporal uint4 (edge stream must not pollute L2;
// cnt slices stay resident).
__global__ __launch_bounds__(256) void k_count(const int* __restrict__ ei, int* __restrict__ cnt) {
    int idx = blockIdx.x * 256 + threadIdx.x;
    if (idx >= METAc * (Ee / 4)) return;
    int m = idx / (Ee / 4), e4 = idx - m * (Ee / 4);
    uint4v d = nt_load4(ei + (size_t)m * 2 * Ee + Ee + e4 * 4);
    int* cm = cnt + m * Nn;
    atomicAdd(cm + (int)d.x, 1);
    atomicAdd(cm + (int)d.y, 1);
    atomicAdd(cm + (int)d.z, 1);
    atomicAdd(cm + (int)d.w, 1);
}

__global__ __launch_bounds__(1024) void k_chunksum(const int* __restrict__ cnt, int* __restrict__ csum) {
    int m = blockIdx.x / NCH, ch = blockIdx.x - m * NCH;
    int tid = threadIdx.x;
    int i = ch * CHUNK + tid;
    int v = (i < Nn) ? cnt[m * Nn + i] : 0;
    #pragma unroll
    for (int o = 1; o < 64; o <<= 1) v += __shfl_xor(v, o);
    __shared__ int ws_[16];
    int lane = tid & 63, w = tid >> 6;
    if (lane == 0) ws_[w] = v;
    __syncthreads();
    if (tid == 0) {
        int s = 0;
        #pragma unroll
        for (int k = 0; k < 16; k++) s += ws_[k];
        csum[m * 64 + ch] = s;
    }
}

__global__ __launch_bounds__(256) void k_chunkscan(int* __restrict__ csum) {
    int tid = threadIdx.x;
    int w = tid >> 6, lane = tid & 63;
    if (w >= METAc) return;
    int v = (lane < NCH) ? csum[w * 64 + lane] : 0;
    int orig = v;
    #pragma unroll
    for (int o = 1; o < 64; o <<= 1) { int t = __shfl_up(v, o); if (lane >= o) v += t; }
    if (lane < NCH) csum[w * 64 + lane] = v - orig;
}

__global__ __launch_bounds__(1024) void k_scan(const int* __restrict__ cnt, const int* __restrict__ csum,
                                               int* __restrict__ off, int* __restrict__ cur,
                                               float* __restrict__ inv) {
    int m = blockIdx.x / NCH, ch = blockIdx.x - m * NCH;
    int tid = threadIdx.x;
    int i = ch * CHUNK + tid;
    int c = (i < Nn) ? cnt[m * Nn + i] : 0;
    int lane = tid & 63, w = tid >> 6;
    int v = c;
    #pragma unroll
    for (int o = 1; o < 64; o <<= 1) { int t = __shfl_up(v, o); if (lane >= o) v += t; }
    __shared__ int ws_[16];
    if (lane == 63) ws_[w] = v;
    __syncthreads();
    if (tid < 16) {
        int s = ws_[tid];
        #pragma unroll
        for (int o = 1; o < 16; o <<= 1) { int t = __shfl_up(s, o); if (lane >= o) s += t; }
        ws_[tid] = s;
    }
    __syncthreads();
    int base = (w > 0) ? ws_[w - 1] : 0;
    if (i < Nn) {
        int g = csum[m * 64 + ch] + base + v - c;
        off[m * Nn + i] = g;
        cur[m * Nn + i] = g;
        inv[m * Nn + i] = 1.0f / fmaxf((float)c, 1.0f);
    }
}

// XCD-local CSR fill. Edge stream read NONTEMPORAL (no L2 allocation) so the
// per-XCD esrc slice (~1 MB) stays L2-resident and dirty lines accumulate
// fully before writeback. 4 edges/thread via uint4.
__global__ __launch_bounds__(256) void k_fill2(const int* __restrict__ ei, int* __restrict__ cur,
                                               int* __restrict__ esrc) {
    const int xcd = blockIdx.x & (NXCD - 1);
    const int wslice = blockIdx.x >> 3;
    const int total4 = METAc * (Ee / 4);
    const int chunk4 = (total4 + FILL_WPX - 1) / FILL_WPX;
    const int beg = wslice * chunk4;
    const int end = (beg + chunk4 < total4) ? beg + chunk4 : total4;
    const int lo = xcd * (Nn / NXCD);
    const int hi = lo + (Nn / NXCD);
    for (int idx = beg + threadIdx.x; idx < end; idx += 256) {
        int m = idx / (Ee / 4), e4 = idx - m * (Ee / 4);
        const int* base = ei + (size_t)m * 2 * Ee;
        uint4v d = nt_load4(base + Ee + e4 * 4);
        uint4v s = nt_load4(base + e4 * 4);
        int* cm = cur + m * Nn;
        int* em = esrc + (size_t)m * Ee;
        int dd;
        dd = (int)d.x; if (dd >= lo && dd < hi) { int p = atomicAdd(cm + dd, 1); em[p] = (int)s.x; }
        dd = (int)d.y; if (dd >= lo && dd < hi) { int p = atomicAdd(cm + dd, 1); em[p] = (int)s.y; }
        dd = (int)d.z; if (dd >= lo && dd < hi) { int p = atomicAdd(cm + dd, 1); em[p] = (int)s.z; }
        dd = (int)d.w; if (dd >= lo && dd < hi) { int p = atomicAdd(cm + dd, 1); em[p] = (int)s.w; }
    }
}

// ============ weight prep ============
__global__ __launch_bounds__(256) void k_wcat(
    const float* __restrict__ W1l, const float* __restrict__ W1r,
    const float* __restrict__ W2l, const float* __restrict__ W2r,
    ushort* __restrict__ Wcat1, ushort* __restrict__ Wcat2)
{
    int idx = blockIdx.x * 256 + threadIdx.x;
    if (idx >= METAc * 384 * 128) return;
    int m = idx / (384 * 128);
    int rem = idx - m * 384 * 128;
    int j = rem >> 7;
    int k = rem & 127;
    if (j < 256) {
        float v = (j < 128) ? W1l[((size_t)m * 128 + k) * 128 + j]
                            : W1r[((size_t)m * 128 + k) * 128 + (j - 128)];
        Wcat1[((size_t)m * 256 + j) * 128 + k] = (ushort)f2bf(v);
    } else {
        int j2 = j - 256;
        float v = (j2 < 64) ? W2l[((size_t)m * 128 + k) * 64 + j2]
                            : W2r[((size_t)m * 128 + k) * 64 + (j2 - 64)];
        Wcat2[((size_t)m * 128 + j2) * 128 + k] = (ushort)f2bf(v);
    }
}

// ============ MFMA GEMM1: t1/r1 = x @ W1{l,r} (+b1 on z==1), bf16 out ============
__global__ __launch_bounds__(256) void k_mfma1(
    const float* __restrict__ x, const ushort* __restrict__ Wcat1,
    const float* __restrict__ b1, ushort* __restrict__ t1, ushort* __restrict__ r1)
{
    const int m = blockIdx.y, z = blockIdx.z;
    const int row0 = blockIdx.x * 128;
    const int tid = threadIdx.x;
    const int lane = tid & 63, w = tid >> 6;
    const int wr = w >> 1, wc = w & 1;

    __shared__ ushort As[128][136];   // 272B rows: 2-way bank aliasing only
    __shared__ ushort Bs[128][136];

    const float* Am = x + (size_t)m * Nn * 128;
    const ushort* Bm = Wcat1 + ((size_t)m * 256 + (size_t)z * 128) * 128;

    #pragma unroll
    for (int i = 0; i < 16; i++) {
        int f4 = tid + i * 256;
        int row = f4 >> 5, c4 = f4 & 31;
        int gr = row0 + row; if (gr >= Nn) gr = Nn - 1;
        float4 v = *(const float4*)(Am + (size_t)gr * 128 + c4 * 4);
        uint lo = f2bf(v.x) | (f2bf(v.y) << 16);
        uint hi = f2bf(v.z) | (f2bf(v.w) << 16);
        *(uint2*)&As[row][c4 * 4] = make_uint2(lo, hi);
    }
    #pragma unroll
    for (int i = 0; i < 8; i++) {
        int c8 = tid + i * 256;
        int row = c8 >> 4, c = c8 & 15;
        *(bf16x8*)&Bs[row][c * 8] = *(const bf16x8*)(Bm + (size_t)row * 128 + c * 8);
    }
    __syncthreads();

    f32x4 acc[4][4];
    #pragma unroll
    for (int i = 0; i < 4; i++)
        #pragma unroll
        for (int j = 0; j < 4; j++) acc[i][j] = (f32x4){0.f, 0.f, 0.f, 0.f};

    #pragma unroll
    for (int ks = 0; ks < 4; ks++) {
        bf16x8 a[4], b[4];
        #pragma unroll
        for (int i = 0; i < 4; i++)
            a[i] = *(const bf16x8*)&As[wr * 64 + i * 16 + (lane & 15)][ks * 32 + (lane >> 4) * 8];
        #pragma unroll
        for (int j = 0; j < 4; j++)
            b[j] = *(const bf16x8*)&Bs[wc * 64 + j * 16 + (lane & 15)][ks * 32 + (lane >> 4) * 8];
        #pragma unroll
        for (int i = 0; i < 4; i++)
            #pragma unroll
            for (int j = 0; j < 4; j++)
                acc[i][j] = mfma16(a[i], b[j], acc[i][j]);
    }

    ushort* outp = (z ? r1 : t1) + (size_t)m * Nn * 128;
    #pragma unroll
    for (int j = 0; j < 4; j++) {
        int col = wc * 64 + j * 16 + (lane & 15);
        float bias = z ? b1[m * 128 + col] : 0.0f;
        #pragma unroll
        for (int i = 0; i < 4; i++) {
            #pragma unroll
            for (int q = 0; q < 4; q++) {
                int row = row0 + wr * 64 + i * 16 + (lane >> 4) * 4 + q;
                if (row < Nn)
                    outp[(size_t)row * 128 + col] = (ushort)f2bf(acc[i][j][q] + bias);
            }
        }
    }
}

// ============ MFMA GEMM2 ============
__global__ __launch_bounds__(256) void k_mfma2(
    const ushort* __restrict__ h, const ushort* __restrict__ Wcat2,
    const float* __restrict__ b2, ushort* __restrict__ t2, ushort* __restrict__ r2)
{
    const int m = blockIdx.y;
    const int row0 = blockIdx.x * 128;
    const int tid = threadIdx.x;
    const int lane = tid & 63, w = tid >> 6;
    const int wr = w >> 1, wc = w & 1;

    __shared__ ushort As[128][136];
    __shared__ ushort Bs[128][136];

    const ushort* Am = h + (size_t)m * Nn * 128;
    const ushort* Bm = Wcat2 + (size_t)m * 128 * 128;

    #pragma unroll
    for (int i = 0; i < 8; i++) {
        int c8 = tid + i * 256;
        int row = c8 >> 4, c = c8 & 15;
        int gr = row0 + row; if (gr >= Nn) gr = Nn - 1;
        *(bf16x8*)&As[row][c * 8] = *(const bf16x8*)(Am + (size_t)gr * 128 + c * 8);
    }
    #pragma unroll
    for (int i = 0; i < 8; i++) {
        int c8 = tid + i * 256;
        int row = c8 >> 4, c = c8 & 15;
        *(bf16x8*)&Bs[row][c * 8] = *(const bf16x8*)(Bm + (size_t)row * 128 + c * 8);
    }
    __syncthreads();

    f32x4 acc[4][4];
    #pragma unroll
    for (int i = 0; i < 4; i++)
        #pragma unroll
        for (int j = 0; j < 4; j++) acc[i][j] = (f32x4){0.f, 0.f, 0.f, 0.f};

    #pragma unroll
    for (int ks = 0; ks < 4; ks++) {
        bf16x8 a[4], b[4];
        #pragma unroll
        for (int i = 0; i < 4; i++)
            a[i] = *(const bf16x8*)&As[wr * 64 + i * 16 + (lane & 15)][ks * 32 + (lane >> 4) * 8];
        #pragma unroll
        for (int j = 0; j < 4; j++)
            b[j] = *(const bf16x8*)&Bs[wc * 64 + j * 16 + (lane & 15)][ks * 32 + (lane >> 4) * 8];
        #pragma unroll
        for (int i = 0; i < 4; i++)
            #pragma unroll
            for (int j = 0; j < 4; j++)
                acc[i][j] = mfma16(a[i], b[j], acc[i][j]);
    }

    ushort* outp = (wc ? r2 : t2) + (size_t)m * Nn * 64;
    #pragma unroll
    for (int j = 0; j < 4; j++) {
        int cl = j * 16 + (lane & 15);
        float bias = wc ? b2[m * 64 + cl] : 0.0f;
        #pragma unroll
        for (int i = 0; i < 4; i++) {
            #pragma unroll
            for (int q = 0; q < 4; q++) {
                int row = row0 + wr * 64 + i * 16 + (lane >> 4) * 4 + q;
                if (row < Nn)
                    outp[(size_t)row * 64 + cl] = (ushort)f2bf(acc[i][j][q] + bias);
            }
        }
    }
}

// ============ agg1: h = ELU(mean-gather(t1) + r1), bf16 ============
__global__ __launch_bounds__(256) void k_agg_elu(
    const ushort* __restrict__ t1, const ushort* __restrict__ r1,
    const int* __restrict__ off, const int* __restrict__ cnt,
    const float* __restrict__ inv, const int* __restrict__ esrc,
    ushort* __restrict__ h)
{
    int gwid = (blockIdx.x * 256 + threadIdx.x) >> 6;
    if (gwid >= METAc * Nn) return;
    int m = gwid / Nn, n = gwid - m * Nn;
    int lane = threadIdx.x & 63;
    int g = lane >> 4;        // 0..3: edge slot
    int sub = lane & 15;      // 16 lanes x 16B = 256B row
    int start = off[m * Nn + n];
    int c = cnt[m * Nn + n];
    const int* es = esrc + (size_t)m * Ee + start;
    const ushort* tm = t1 + (size_t)m * Nn * 128;

    f32x2 a[4];
    #pragma unroll
    for (int k = 0; k < 4; k++) a[k] = (f32x2){0.f, 0.f};

    int nfull = c & ~15;
    for (int e = 0; e < nfull; e += 16) {
        int s0 = es[e + g];
        int s1 = es[e + 4 + g];
        int s2 = es[e + 8 + g];
        int s3 = es[e + 12 + g];
        uint4 v0 = *(const uint4*)(tm + (size_t)s0 * 128 + sub * 8);
        uint4 v1 = *(const uint4*)(tm + (size_t)s1 * 128 + sub * 8);
        uint4 v2 = *(const uint4*)(tm + (size_t)s2 * 128 + sub * 8);
        uint4 v3 = *(const uint4*)(tm + (size_t)s3 * 128 + sub * 8);
        a[0] += up2(v0.x); a[1] += up2(v0.y); a[2] += up2(v0.z); a[3] += up2(v0.w);
        a[0] += up2(v1.x); a[1] += up2(v1.y); a[2] += up2(v1.z); a[3] += up2(v1.w);
        a[0] += up2(v2.x); a[1] += up2(v2.y); a[2] += up2(v2.z); a[3] += up2(v2.w);
        a[0] += up2(v3.x); a[1] += up2(v3.y); a[2] += up2(v3.z); a[3] += up2(v3.w);
    }
    for (int e = nfull + g; e < c; e += 4) {   // divergent tail, no clamps
        int s0 = es[e];
        uint4 v0 = *(const uint4*)(tm + (size_t)s0 * 128 + sub * 8);
        a[0] += up2(v0.x); a[1] += up2(v0.y); a[2] += up2(v0.z); a[3] += up2(v0.w);
    }
    #pragma unroll
    for (int k = 0; k < 4; k++) {
        a[k].x += __shfl_xor(a[k].x, 16);  a[k].y += __shfl_xor(a[k].y, 16);
        a[k].x += __shfl_xor(a[k].x, 32);  a[k].y += __shfl_xor(a[k].y, 32);
    }

    float iv = inv[m * Nn + n];
    uint4 rv = *(const uint4*)(r1 + ((size_t)m * Nn + n) * 128 + sub * 8);
    uint rr[4] = {rv.x, rv.y, rv.z, rv.w};
    uint o[4];
    #pragma unroll
    for (int k = 0; k < 4; k++) {
        float z0 = a[k].x * iv + bf2f(rr[k] & 0xffffu);
        float z1 = a[k].y * iv + bf2f(rr[k] >> 16);
        z0 = z0 > 0.0f ? z0 : expm1f(z0);
        z1 = z1 > 0.0f ? z1 : expm1f(z1);
        o[k] = f2bf(z0) | (f2bf(z1) << 16);
    }
    if (g == 0) {
        *(uint4*)(h + ((size_t)m * Nn + n) * 128 + sub * 8) = make_uint4(o[0], o[1], o[2], o[3]);
    }
}

// ============ agg2: out = log_softmax(mean-gather(t2) + r2) ============
__global__ __launch_bounds__(256) void k_agg_lsm(
    const ushort* __restrict__ t2, const ushort* __restrict__ r2,
    const int* __restrict__ off, const int* __restrict__ cnt,
    const float* __restrict__ inv, const int* __restrict__ esrc,
    float* __restrict__ out)
{
    int gwid = (blockIdx.x * 256 + threadIdx.x) >> 6;
    if (gwid >= METAc * Nn) return;
    int m = gwid / Nn, n = gwid - m * Nn;
    int lane = threadIdx.x & 63;
    int g = lane >> 3;        // 0..7: edge slot
    int sub = lane & 7;       // 8 lanes x 16B = 128B row
    int start = off[m * Nn + n];
    int c = cnt[m * Nn + n];
    const int* es = esrc + (size_t)m * Ee + start;
    const ushort* tm = t2 + (size_t)m * Nn * 64;

    f32x2 a[4];
    #pragma unroll
    for (int k = 0; k < 4; k++) a[k] = (f32x2){0.f, 0.f};

    int nfull = c & ~15;
    for (int e = 0; e < nfull; e += 16) {
        int s0 = es[e + g];
        int s1 = es[e + 8 + g];
        uint4 v0 = *(const uint4*)(tm + (size_t)s0 * 64 + sub * 8);
        uint4 v1 = *(const uint4*)(tm + (size_t)s1 * 64 + sub * 8);
        a[0] += up2(v0.x); a[1] += up2(v0.y); a[2] += up2(v0.z); a[3] += up2(v0.w);
        a[0] += up2(v1.x); a[1] += up2(v1.y); a[2] += up2(v1.z); a[3] += up2(v1.w);
    }
    for (int e = nfull + g; e < c; e += 8) {   // divergent tail
        int s0 = es[e];
        uint4 v0 = *(const uint4*)(tm + (size_t)s0 * 64 + sub * 8);
        a[0] += up2(v0.x); a[1] += up2(v0.y); a[2] += up2(v0.z); a[3] += up2(v0.w);
    }
    #pragma unroll
    for (int k = 0; k < 4; k++) {
        a[k].x += __shfl_xor(a[k].x, 8);   a[k].y += __shfl_xor(a[k].y, 8);
        a[k].x += __shfl_xor(a[k].x, 16);  a[k].y += __shfl_xor(a[k].y, 16);
        a[k].x += __shfl_xor(a[k].x, 32);  a[k].y += __shfl_xor(a[k].y, 32);
    }

    float iv = inv[m * Nn + n];
    uint4 rv = *(const uint4*)(r2 + ((size_t)m * Nn + n) * 64 + sub * 8);
    uint rr[4] = {rv.x, rv.y, rv.z, rv.w};
    float z[8];
    #pragma unroll
    for (int k = 0; k < 4; k++) {
        z[2 * k]     = a[k].x * iv + bf2f(rr[k] & 0xffffu);
        z[2 * k + 1] = a[k].y * iv + bf2f(rr[k] >> 16);
    }
    float mx = z[0];
    #pragma unroll
    for (int k = 1; k < 8; k++) mx = fmaxf(mx, z[k]);
    #pragma unroll
    for (int o = 1; o <= 4; o <<= 1) mx = fmaxf(mx, __shfl_xor(mx, o));
    float s = 0.0f;
    #pragma unroll
    for (int k = 0; k < 8; k++) s += expf(z[k] - mx);
    #pragma unroll
    for (int o = 1; o <= 4; o <<= 1) s += __shfl_xor(s, o);
    float lse = mx + logf(s);
    if (g == 0) {
        float* op = out + ((size_t)m * Nn + n) * 64 + sub * 8;
        *(float4*)op       = make_float4(z[0] - lse, z[1] - lse, z[2] - lse, z[3] - lse);
        *(float4*)(op + 4) = make_float4(z[4] - lse, z[5] - lse, z[6] - lse, z[7] - lse);
    }
}

extern "C" void kernel_launch(void* const* d_in, const int* in_sizes, int n_in,
                              void* d_out, int out_size, void* d_ws, size_t ws_size,
                              hipStream_t stream) {
    const float* meta_x = (const float*)d_in[0];
    const int*   ei     = (const int*)d_in[1];
    const float* W1l    = (const float*)d_in[2];
    const float* W1r    = (const float*)d_in[3];
    const float* b1     = (const float*)d_in[4];
    const float* W2l    = (const float*)d_in[5];
    const float* W2r    = (const float*)d_in[6];
    const float* b2     = (const float*)d_in[7];
    float* out = (float*)d_out;

    const size_t nN = (size_t)METAc * Nn;

    float* inv  = (float*)d_ws;
    int*   cnt  = (int*)(inv + nN);
    int*   off  = cnt + nN;
    int*   cur  = off + nN;
    int*   csum = cur + nN;
    int*   esrc = csum + 64 * METAc;
    ushort* t1  = (ushort*)(esrc + (size_t)METAc * Ee);
    ushort* r1  = t1 + nN * 128;
    ushort* h   = r1 + nN * 128;
    ushort* t2  = h + nN * 128;
    ushort* r2  = t2 + nN * 64;
    ushort* Wcat1 = r2 + nN * 64;                       // META*256*128
    ushort* Wcat2 = Wcat1 + (size_t)METAc * 256 * 128;  // META*128*128

    (void)hipMemsetAsync(cnt, 0, nN * sizeof(int), stream);
    k_count<<<(METAc * (Ee / 4) + 255) / 256, 256, 0, stream>>>(ei, cnt);
    k_chunksum<<<METAc * NCH, 1024, 0, stream>>>(cnt, csum);
    k_chunkscan<<<1, 256, 0, stream>>>(csum);
    k_scan<<<METAc * NCH, 1024, 0, stream>>>(cnt, csum, off, cur, inv);
    k_fill2<<<NXCD * FILL_WPX, 256, 0, stream>>>(ei, cur, esrc);
    k_wcat<<<(METAc * 384 * 128 + 255) / 256, 256, 0, stream>>>(W1l, W1r, W2l, W2r, Wcat1, Wcat2);

    k_mfma1<<<dim3((Nn + 127) / 128, METAc, 2), 256, 0, stream>>>(meta_x, Wcat1, b1, t1, r1);
    k_agg_elu<<<(METAc * Nn * 64 + 255) / 256, 256, 0, stream>>>(t1, r1, off, cnt, inv, esrc, h);
    k_mfma2<<<dim3((Nn + 127) / 128, METAc, 1), 256, 0, stream>>>(h, Wcat2, b2, t2, r2);
    k_agg_lsm<<<(METAc * Nn * 64 + 255) / 256, 256, 0, stream>>>(t2, r2, off, cnt, inv, esrc, out);
}

// Round 10
// 442.453 us; speedup vs baseline: 15.3065x; 1.0301x over previous
//
#include <hip/hip_runtime.h>

#define METAc 3
#define Nn 50000
#define Ee 640000
#define CHUNK 1024
#define NCH 49   // ceil(Nn/CHUNK)
#define NXCD 8
#define FILL_WPX 256   // workgroups per XCD-slice for k_fill2

typedef unsigned int uint;
typedef unsigned short ushort;
typedef __attribute__((ext_vector_type(8))) short bf16x8;
typedef __attribute__((ext_vector_type(4))) float f32x4;
typedef __attribute__((ext_vector_type(2))) float f32x2;
typedef __attribute__((ext_vector_type(4))) uint uint4v;   // native vector: OK for nontemporal builtins

__device__ __forceinline__ float bf2f(uint u16) {
    union { uint u; float f; } v; v.u = u16 << 16; return v.f;
}
__device__ __forceinline__ uint f2bf(float f) {
    union { float f; uint u; } v; v.f = f;
    return (v.u + 0x7fffu + ((v.u >> 16) & 1u)) >> 16;
}
// unpack 2 packed bf16 -> float2 {lo, hi}; add is 1 v_pk_add_f32
__device__ __forceinline__ f32x2 up2(uint u) {
    union { uint2 u2; f32x2 f; } cv;
    cv.u2.x = u << 16;
    cv.u2.y = u & 0xffff0000u;
    return cv.f;
}
__device__ __forceinline__ f32x4 mfma16(bf16x8 a, bf16x8 b, f32x4 c) {
    return __builtin_amdgcn_mfma_f32_16x16x32_bf16(a, b, c, 0, 0, 0);
}
__device__ __forceinline__ uint4v nt_load4(const void* p) {
    return __builtin_nontemporal_load((const uint4v*)p);
}

// ================= CSR build =================
__global__ __launch_bounds__(256) void k_count(const int* __restrict__ ei, int* __restrict__ cnt) {
    int idx = blockIdx.x * 256 + threadIdx.x;
    if (idx >= METAc * (Ee / 4)) return;
    int m = idx / (Ee / 4), e4 = idx - m * (Ee / 4);
    uint4v d = nt_load4(ei + (size_t)m * 2 * Ee + Ee + e4 * 4);
    int* cm = cnt + m * Nn;
    atomicAdd(cm + (int)d.x, 1);
    atomicAdd(cm + (int)d.y, 1);
    atomicAdd(cm + (int)d.z, 1);
    atomicAdd(cm + (int)d.w, 1);
}

__global__ __launch_bounds__(1024) void k_chunksum(const int* __restrict__ cnt, int* __restrict__ csum) {
    int m = blockIdx.x / NCH, ch = blockIdx.x - m * NCH;
    int tid = threadIdx.x;
    int i = ch * CHUNK + tid;
    int v = (i < Nn) ? cnt[m * Nn + i] : 0;
    #pragma unroll
    for (int o = 1; o < 64; o <<= 1) v += __shfl_xor(v, o);
    __shared__ int ws_[16];
    int lane = tid & 63, w = tid >> 6;
    if (lane == 0) ws_[w] = v;
    __syncthreads();
    if (tid == 0) {
        int s = 0;
        #pragma unroll
        for (int k = 0; k < 16; k++) s += ws_[k];
        csum[m * 64 + ch] = s;
    }
}

__global__ __launch_bounds__(256) void k_chunkscan(int* __restrict__ csum) {
    int tid = threadIdx.x;
    int w = tid >> 6, lane = tid & 63;
    if (w >= METAc) return;
    int v = (lane < NCH) ? csum[w * 64 + lane] : 0;
    int orig = v;
    #pragma unroll
    for (int o = 1; o < 64; o <<= 1) { int t = __shfl_up(v, o); if (lane >= o) v += t; }
    if (lane < NCH) csum[w * 64 + lane] = v - orig;
}

__global__ __launch_bounds__(1024) void k_scan(const int* __restrict__ cnt, const int* __restrict__ csum,
                                               int* __restrict__ off, int* __restrict__ cur,
                                               float* __restrict__ inv) {
    int m = blockIdx.x / NCH, ch = blockIdx.x - m * NCH;
    int tid = threadIdx.x;
    int i = ch * CHUNK + tid;
    int c = (i < Nn) ? cnt[m * Nn + i] : 0;
    int lane = tid & 63, w = tid >> 6;
    int v = c;
    #pragma unroll
    for (int o = 1; o < 64; o <<= 1) { int t = __shfl_up(v, o); if (lane >= o) v += t; }
    __shared__ int ws_[16];
    if (lane == 63) ws_[w] = v;
    __syncthreads();
    if (tid < 16) {
        int s = ws_[tid];
        #pragma unroll
        for (int o = 1; o < 16; o <<= 1) { int t = __shfl_up(s, o); if (lane >= o) s += t; }
        ws_[tid] = s;
    }
    __syncthreads();
    int base = (w > 0) ? ws_[w - 1] : 0;
    if (i < Nn) {
        int g = csum[m * 64 + ch] + base + v - c;
        off[m * Nn + i] = g;
        cur[m * Nn + i] = g;
        inv[m * Nn + i] = 1.0f / fmaxf((float)c, 1.0f);
    }
}

// XCD-local CSR fill; edge stream nontemporal.
__global__ __launch_bounds__(256) void k_fill2(const int* __restrict__ ei, int* __restrict__ cur,
                                               int* __restrict__ esrc) {
    const int xcd = blockIdx.x & (NXCD - 1);
    const int wslice = blockIdx.x >> 3;
    const int total4 = METAc * (Ee / 4);
    const int chunk4 = (total4 + FILL_WPX - 1) / FILL_WPX;
    const int beg = wslice * chunk4;
    const int end = (beg + chunk4 < total4) ? beg + chunk4 : total4;
    const int lo = xcd * (Nn / NXCD);
    const int hi = lo + (Nn / NXCD);
    for (int idx = beg + threadIdx.x; idx < end; idx += 256) {
        int m = idx / (Ee / 4), e4 = idx - m * (Ee / 4);
        const int* base = ei + (size_t)m * 2 * Ee;
        uint4v d = nt_load4(base + Ee + e4 * 4);
        uint4v s = nt_load4(base + e4 * 4);
        int* cm = cur + m * Nn;
        int* em = esrc + (size_t)m * Ee;
        int dd;
        dd = (int)d.x; if (dd >= lo && dd < hi) { int p = atomicAdd(cm + dd, 1); em[p] = (int)s.x; }
        dd = (int)d.y; if (dd >= lo && dd < hi) { int p = atomicAdd(cm + dd, 1); em[p] = (int)s.y; }
        dd = (int)d.z; if (dd >= lo && dd < hi) { int p = atomicAdd(cm + dd, 1); em[p] = (int)s.z; }
        dd = (int)d.w; if (dd >= lo && dd < hi) { int p = atomicAdd(cm + dd, 1); em[p] = (int)s.w; }
    }
}

// ============ weight prep ============
__global__ __launch_bounds__(256) void k_wcat(
    const float* __restrict__ W1l, const float* __restrict__ W1r,
    const float* __restrict__ W2l, const float* __restrict__ W2r,
    ushort* __restrict__ Wcat1, ushort* __restrict__ Wcat2)
{
    int idx = blockIdx.x * 256 + threadIdx.x;
    if (idx >= METAc * 384 * 128) return;
    int m = idx / (384 * 128);
    int rem = idx - m * 384 * 128;
    int j = rem >> 7;
    int k = rem & 127;
    if (j < 256) {
        float v = (j < 128) ? W1l[((size_t)m * 128 + k) * 128 + j]
                            : W1r[((size_t)m * 128 + k) * 128 + (j - 128)];
        Wcat1[((size_t)m * 256 + j) * 128 + k] = (ushort)f2bf(v);
    } else {
        int j2 = j - 256;
        float v = (j2 < 64) ? W2l[((size_t)m * 128 + k) * 64 + j2]
                            : W2r[((size_t)m * 128 + k) * 64 + (j2 - 64)];
        Wcat2[((size_t)m * 128 + j2) * 128 + k] = (ushort)f2bf(v);
    }
}

// ============ MFMA GEMM1: t1/r1 = x @ W1{l,r} (+b1 on z==1), bf16 out ============
__global__ __launch_bounds__(256) void k_mfma1(
    const float* __restrict__ x, const ushort* __restrict__ Wcat1,
    const float* __restrict__ b1, ushort* __restrict__ t1, ushort* __restrict__ r1)
{
    const int m = blockIdx.y, z = blockIdx.z;
    const int row0 = blockIdx.x * 128;
    const int tid = threadIdx.x;
    const int lane = tid & 63, w = tid >> 6;
    const int wr = w >> 1, wc = w & 1;

    __shared__ ushort As[128][136];   // 272B rows: 2-way bank aliasing only
    __shared__ ushort Bs[128][136];

    const float* Am = x + (size_t)m * Nn * 128;
    const ushort* Bm = Wcat1 + ((size_t)m * 256 + (size_t)z * 128) * 128;

    #pragma unroll
    for (int i = 0; i < 16; i++) {
        int f4 = tid + i * 256;
        int row = f4 >> 5, c4 = f4 & 31;
        int gr = row0 + row; if (gr >= Nn) gr = Nn - 1;
        float4 v = *(const float4*)(Am + (size_t)gr * 128 + c4 * 4);
        uint lo = f2bf(v.x) | (f2bf(v.y) << 16);
        uint hi = f2bf(v.z) | (f2bf(v.w) << 16);
        *(uint2*)&As[row][c4 * 4] = make_uint2(lo, hi);
    }
    #pragma unroll
    for (int i = 0; i < 8; i++) {
        int c8 = tid + i * 256;
        int row = c8 >> 4, c = c8 & 15;
        *(bf16x8*)&Bs[row][c * 8] = *(const bf16x8*)(Bm + (size_t)row * 128 + c * 8);
    }
    __syncthreads();

    f32x4 acc[4][4];
    #pragma unroll
    for (int i = 0; i < 4; i++)
        #pragma unroll
        for (int j = 0; j < 4; j++) acc[i][j] = (f32x4){0.f, 0.f, 0.f, 0.f};

    #pragma unroll
    for (int ks = 0; ks < 4; ks++) {
        bf16x8 a[4], b[4];
        #pragma unroll
        for (int i = 0; i < 4; i++)
            a[i] = *(const bf16x8*)&As[wr * 64 + i * 16 + (lane & 15)][ks * 32 + (lane >> 4) * 8];
        #pragma unroll
        for (int j = 0; j < 4; j++)
            b[j] = *(const bf16x8*)&Bs[wc * 64 + j * 16 + (lane & 15)][ks * 32 + (lane >> 4) * 8];
        #pragma unroll
        for (int i = 0; i < 4; i++)
            #pragma unroll
            for (int j = 0; j < 4; j++)
                acc[i][j] = mfma16(a[i], b[j], acc[i][j]);
    }

    ushort* outp = (z ? r1 : t1) + (size_t)m * Nn * 128;
    #pragma unroll
    for (int j = 0; j < 4; j++) {
        int col = wc * 64 + j * 16 + (lane & 15);
        float bias = z ? b1[m * 128 + col] : 0.0f;
        #pragma unroll
        for (int i = 0; i < 4; i++) {
            #pragma unroll
            for (int q = 0; q < 4; q++) {
                int row = row0 + wr * 64 + i * 16 + (lane >> 4) * 4 + q;
                if (row < Nn)
                    outp[(size_t)row * 128 + col] = (ushort)f2bf(acc[i][j][q] + bias);
            }
        }
    }
}

// ============ MFMA GEMM2 ============
__global__ __launch_bounds__(256) void k_mfma2(
    const ushort* __restrict__ h, const ushort* __restrict__ Wcat2,
    const float* __restrict__ b2, ushort* __restrict__ t2, ushort* __restrict__ r2)
{
    const int m = blockIdx.y;
    const int row0 = blockIdx.x * 128;
    const int tid = threadIdx.x;
    const int lane = tid & 63, w = tid >> 6;
    const int wr = w >> 1, wc = w & 1;

    __shared__ ushort As[128][136];
    __shared__ ushort Bs[128][136];

    const ushort* Am = h + (size_t)m * Nn * 128;
    const ushort* Bm = Wcat2 + (size_t)m * 128 * 128;

    #pragma unroll
    for (int i = 0; i < 8; i++) {
        int c8 = tid + i * 256;
        int row = c8 >> 4, c = c8 & 15;
        int gr = row0 + row; if (gr >= Nn) gr = Nn - 1;
        *(bf16x8*)&As[row][c * 8] = *(const bf16x8*)(Am + (size_t)gr * 128 + c * 8);
    }
    #pragma unroll
    for (int i = 0; i < 8; i++) {
        int c8 = tid + i * 256;
        int row = c8 >> 4, c = c8 & 15;
        *(bf16x8*)&Bs[row][c * 8] = *(const bf16x8*)(Bm + (size_t)row * 128 + c * 8);
    }
    __syncthreads();

    f32x4 acc[4][4];
    #pragma unroll
    for (int i = 0; i < 4; i++)
        #pragma unroll
        for (int j = 0; j < 4; j++) acc[i][j] = (f32x4){0.f, 0.f, 0.f, 0.f};

    #pragma unroll
    for (int ks = 0; ks < 4; ks++) {
        bf16x8 a[4], b[4];
        #pragma unroll
        for (int i = 0; i < 4; i++)
            a[i] = *(const bf16x8*)&As[wr * 64 + i * 16 + (lane & 15)][ks * 32 + (lane >> 4) * 8];
        #pragma unroll
        for (int j = 0; j < 4; j++)
            b[j] = *(const bf16x8*)&Bs[wc * 64 + j * 16 + (lane & 15)][ks * 32 + (lane >> 4) * 8];
        #pragma unroll
        for (int i = 0; i < 4; i++)
            #pragma unroll
            for (int j = 0; j < 4; j++)
                acc[i][j] = mfma16(a[i], b[j], acc[i][j]);
    }

    ushort* outp = (wc ? r2 : t2) + (size_t)m * Nn * 64;
    #pragma unroll
    for (int j = 0; j < 4; j++) {
        int cl = j * 16 + (lane & 15);
        float bias = wc ? b2[m * 64 + cl] : 0.0f;
        #pragma unroll
        for (int i = 0; i < 4; i++) {
            #pragma unroll
            for (int q = 0; q < 4; q++) {
                int row = row0 + wr * 64 + i * 16 + (lane >> 4) * 4 + q;
                if (row < Nn)
                    outp[(size_t)row * 64 + cl] = (ushort)f2bf(acc[i][j][q] + bias);
            }
        }
    }
}

// ============ agg1: h = ELU(mean-gather(t1) + r1), bf16 ============
// Fast ELU: __expf (v_exp_f32) instead of libm expm1f — bf16 output makes the
// ~1e-7 absolute error of exp(z)-1 vs expm1(z) invisible.
__global__ __launch_bounds__(256) void k_agg_elu(
    const ushort* __restrict__ t1, const ushort* __restrict__ r1,
    const int* __restrict__ off, const int* __restrict__ cnt,
    const float* __restrict__ inv, const int* __restrict__ esrc,
    ushort* __restrict__ h)
{
    int gwid = (blockIdx.x * 256 + threadIdx.x) >> 6;
    if (gwid >= METAc * Nn) return;
    int m = gwid / Nn, n = gwid - m * Nn;
    int lane = threadIdx.x & 63;
    int g = lane >> 4;        // 0..3: edge slot
    int sub = lane & 15;      // 16 lanes x 16B = 256B row
    int start = off[m * Nn + n];
    int c = cnt[m * Nn + n];
    const int* es = esrc + (size_t)m * Ee + start;
    const ushort* tm = t1 + (size_t)m * Nn * 128;

    f32x2 a[4];
    #pragma unroll
    for (int k = 0; k < 4; k++) a[k] = (f32x2){0.f, 0.f};

    int nfull = c & ~15;
    for (int e = 0; e < nfull; e += 16) {
        int s0 = es[e + g];
        int s1 = es[e + 4 + g];
        int s2 = es[e + 8 + g];
        int s3 = es[e + 12 + g];
        uint4 v0 = *(const uint4*)(tm + (size_t)s0 * 128 + sub * 8);
        uint4 v1 = *(const uint4*)(tm + (size_t)s1 * 128 + sub * 8);
        uint4 v2 = *(const uint4*)(tm + (size_t)s2 * 128 + sub * 8);
        uint4 v3 = *(const uint4*)(tm + (size_t)s3 * 128 + sub * 8);
        a[0] += up2(v0.x); a[1] += up2(v0.y); a[2] += up2(v0.z); a[3] += up2(v0.w);
        a[0] += up2(v1.x); a[1] += up2(v1.y); a[2] += up2(v1.z); a[3] += up2(v1.w);
        a[0] += up2(v2.x); a[1] += up2(v2.y); a[2] += up2(v2.z); a[3] += up2(v2.w);
        a[0] += up2(v3.x); a[1] += up2(v3.y); a[2] += up2(v3.z); a[3] += up2(v3.w);
    }
    for (int e = nfull + g; e < c; e += 4) {   // divergent tail, no clamps
        int s0 = es[e];
        uint4 v0 = *(const uint4*)(tm + (size_t)s0 * 128 + sub * 8);
        a[0] += up2(v0.x); a[1] += up2(v0.y); a[2] += up2(v0.z); a[3] += up2(v0.w);
    }
    #pragma unroll
    for (int k = 0; k < 4; k++) {
        a[k].x += __shfl_xor(a[k].x, 16);  a[k].y += __shfl_xor(a[k].y, 16);
        a[k].x += __shfl_xor(a[k].x, 32);  a[k].y += __shfl_xor(a[k].y, 32);
    }

    float iv = inv[m * Nn + n];
    uint4 rv = *(const uint4*)(r1 + ((size_t)m * Nn + n) * 128 + sub * 8);
    uint rr[4] = {rv.x, rv.y, rv.z, rv.w};
    uint o[4];
    #pragma unroll
    for (int k = 0; k < 4; k++) {
        float z0 = a[k].x * iv + bf2f(rr[k] & 0xffffu);
        float z1 = a[k].y * iv + bf2f(rr[k] >> 16);
        z0 = z0 > 0.0f ? z0 : (__expf(z0) - 1.0f);
        z1 = z1 > 0.0f ? z1 : (__expf(z1) - 1.0f);
        o[k] = f2bf(z0) | (f2bf(z1) << 16);
    }
    if (g == 0) {
        *(uint4*)(h + ((size_t)m * Nn + n) * 128 + sub * 8) = make_uint4(o[0], o[1], o[2], o[3]);
    }
}

// ============ agg2: out = log_softmax(mean-gather(t2) + r2) ============
// Fast softmax: __expf / __logf hardware transcendentals.
__global__ __launch_bounds__(256) void k_agg_lsm(
    const ushort* __restrict__ t2, const ushort* __restrict__ r2,
    const int* __restrict__ off, const int* __restrict__ cnt,
    const float* __restrict__ inv, const int* __restrict__ esrc,
    float* __restrict__ out)
{
    int gwid = (blockIdx.x * 256 + threadIdx.x) >> 6;
    if (gwid >= METAc * Nn) return;
    int m = gwid / Nn, n = gwid - m * Nn;
    int lane = threadIdx.x & 63;
    int g = lane >> 3;        // 0..7: edge slot
    int sub = lane & 7;       // 8 lanes x 16B = 128B row
    int start = off[m * Nn + n];
    int c = cnt[m * Nn + n];
    const int* es = esrc + (size_t)m * Ee + start;
    const ushort* tm = t2 + (size_t)m * Nn * 64;

    f32x2 a[4];
    #pragma unroll
    for (int k = 0; k < 4; k++) a[k] = (f32x2){0.f, 0.f};

    int nfull = c & ~15;
    for (int e = 0; e < nfull; e += 16) {
        int s0 = es[e + g];
        int s1 = es[e + 8 + g];
        uint4 v0 = *(const uint4*)(tm + (size_t)s0 * 64 + sub * 8);
        uint4 v1 = *(const uint4*)(tm + (size_t)s1 * 64 + sub * 8);
        a[0] += up2(v0.x); a[1] += up2(v0.y); a[2] += up2(v0.z); a[3] += up2(v0.w);
        a[0] += up2(v1.x); a[1] += up2(v1.y); a[2] += up2(v1.z); a[3] += up2(v1.w);
    }
    for (int e = nfull + g; e < c; e += 8) {   // divergent tail
        int s0 = es[e];
        uint4 v0 = *(const uint4*)(tm + (size_t)s0 * 64 + sub * 8);
        a[0] += up2(v0.x); a[1] += up2(v0.y); a[2] += up2(v0.z); a[3] += up2(v0.w);
    }
    #pragma unroll
    for (int k = 0; k < 4; k++) {
        a[k].x += __shfl_xor(a[k].x, 8);   a[k].y += __shfl_xor(a[k].y, 8);
        a[k].x += __shfl_xor(a[k].x, 16);  a[k].y += __shfl_xor(a[k].y, 16);
        a[k].x += __shfl_xor(a[k].x, 32);  a[k].y += __shfl_xor(a[k].y, 32);
    }

    float iv = inv[m * Nn + n];
    uint4 rv = *(const uint4*)(r2 + ((size_t)m * Nn + n) * 64 + sub * 8);
    uint rr[4] = {rv.x, rv.y, rv.z, rv.w};
    float z[8];
    #pragma unroll
    for (int k = 0; k < 4; k++) {
        z[2 * k]     = a[k].x * iv + bf2f(rr[k] & 0xffffu);
        z[2 * k + 1] = a[k].y * iv + bf2f(rr[k] >> 16);
    }
    float mx = z[0];
    #pragma unroll
    for (int k = 1; k < 8; k++) mx = fmaxf(mx, z[k]);
    #pragma unroll
    for (int o = 1; o <= 4; o <<= 1) mx = fmaxf(mx, __shfl_xor(mx, o));
    float s = 0.0f;
    #pragma unroll
    for (int k = 0; k < 8; k++) s += __expf(z[k] - mx);
    #pragma unroll
    for (int o = 1; o <= 4; o <<= 1) s += __shfl_xor(s, o);
    float lse = mx + __logf(s);
    if (g == 0) {
        float* op = out + ((size_t)m * Nn + n) * 64 + sub * 8;
        *(float4*)op       = make_float4(z[0] - lse, z[1] - lse, z[2] - lse, z[3] - lse);
        *(float4*)(op + 4) = make_float4(z[4] - lse, z[5] - lse, z[6] - lse, z[7] - lse);
    }
}

extern "C" void kernel_launch(void* const* d_in, const int* in_sizes, int n_in,
                              void* d_out, int out_size, void* d_ws, size_t ws_size,
                              hipStream_t stream) {
    const float* meta_x = (const float*)d_in[0];
    const int*   ei     = (const int*)d_in[1];
    const float* W1l    = (const float*)d_in[2];
    const float* W1r    = (const float*)d_in[3];
    const float* b1     = (const float*)d_in[4];
    const float* W2l    = (const float*)d_in[5];
    const float* W2r    = (const float*)d_in[6];
    const float* b2     = (const float*)d_in[7];
    float* out = (float*)d_out;

    const size_t nN = (size_t)METAc * Nn;

    float* inv  = (float*)d_ws;
    int*   cnt  = (int*)(inv + nN);
    int*   off  = cnt + nN;
    int*   cur  = off + nN;
    int*   csum = cur + nN;
    int*   esrc = csum + 64 * METAc;
    ushort* t1  = (ushort*)(esrc + (size_t)METAc * Ee);
    ushort* r1  = t1 + nN * 128;
    ushort* h   = r1 + nN * 128;
    ushort* t2  = h + nN * 128;
    ushort* r2  = t2 + nN * 64;
    ushort* Wcat1 = r2 + nN * 64;                       // META*256*128
    ushort* Wcat2 = Wcat1 + (size_t)METAc * 256 * 128;  // META*128*128

    (void)hipMemsetAsync(cnt, 0, nN * sizeof(int), stream);
    k_count<<<(METAc * (Ee / 4) + 255) / 256, 256, 0, stream>>>(ei, cnt);
    k_chunksum<<<METAc * NCH, 1024, 0, stream>>>(cnt, csum);
    k_chunkscan<<<1, 256, 0, stream>>>(csum);
    k_scan<<<METAc * NCH, 1024, 0, stream>>>(cnt, csum, off, cur, inv);
    k_fill2<<<NXCD * FILL_WPX, 256, 0, stream>>>(ei, cur, esrc);
    k_wcat<<<(METAc * 384 * 128 + 255) / 256, 256, 0, stream>>>(W1l, W1r, W2l, W2r, Wcat1, Wcat2);

    k_mfma1<<<dim3((Nn + 127) / 128, METAc, 2), 256, 0, stream>>>(meta_x, Wcat1, b1, t1, r1);
    k_agg_elu<<<(METAc * Nn * 64 + 255) / 256, 256, 0, stream>>>(t1, r1, off, cnt, inv, esrc, h);
    k_mfma2<<<dim3((Nn + 127) / 128, METAc, 1), 256, 0, stream>>>(h, Wcat2, b2, t2, r2);
    k_agg_lsm<<<(METAc * Nn * 64 + 255) / 256, 256, 0, stream>>>(t2, r2, off, cnt, inv, esrc, out);
}